// Round 3
// baseline (4633.761 us; speedup 1.0000x reference)
//
#include <hip/hip_runtime.h>
#include <hip/hip_bf16.h>
#include <math.h>

#define B_SZ 2
#define L_SZ 4096
#define D_MODEL_ 1024
#define D_INNER_ 2048
#define D_STATE_ 16
#define D_CONV_ 4
#define DT_RANK_ 64

typedef unsigned short ushort8 __attribute__((ext_vector_type(8)));

__device__ __forceinline__ float bf2f(unsigned short b) {
    return __uint_as_float(((unsigned)b) << 16);
}
__device__ __forceinline__ unsigned short f2bf(float f) {
    unsigned u = __float_as_uint(f);
    unsigned r = (u + 0x7fffu + ((u >> 16) & 1u)) >> 16;  // RNE
    return (unsigned short)r;
}
__device__ __forceinline__ float softplus_f(float x) {
    return (x > 20.f) ? x : log1pf(__expf(x));
}
__device__ __forceinline__ float silu_f(float x) {
    return x / (1.f + __expf(-x));
}

// Tiled GEMM: C = act(A[M,K(lda)] @ W[N,K]^T), f32 accumulate in VALU.
// TA: float or ushort(bf16). TO: float or ushort(bf16).
// ACT 0: plain write to C0 (row stride N)
// ACT 1: split cols: col < D_INNER -> C0 else C1 (both row stride D_INNER, bf16)
// ACT 2: delta epilogue: softplus(softplus(v + bias[col]) + bias[col])
template<typename TA, typename TO, int BM, int BN, int BK, int TM, int TN, int ACT>
__global__ __launch_bounds__(256) void gemm_t(
    const TA* __restrict__ Am, int lda,
    const float* __restrict__ Wm,
    const float* __restrict__ bias,
    TO* __restrict__ C0, TO* __restrict__ C1,
    int M, int N, int K)
{
    constexpr int TX = BN / TN;
    constexpr int TY = BM / TM;
    static_assert(TX * TY == 256, "bad tiling");
    __shared__ float As[BM][BK + 1];
    __shared__ float Ws[BN][BK + 1];
    const int tid = threadIdx.x;
    const int tx = tid % TX, ty = tid / TX;
    const int m0 = blockIdx.y * BM;
    const int n0 = blockIdx.x * BN;

    float acc[TM][TN];
#pragma unroll
    for (int i = 0; i < TM; i++)
#pragma unroll
        for (int j = 0; j < TN; j++) acc[i][j] = 0.f;

    for (int k0 = 0; k0 < K; k0 += BK) {
        // ---- stage A tile ----
        if constexpr (sizeof(TA) == 4) {
            constexpr int KF4 = BK / 4;
            for (int i = tid; i < BM * KF4; i += 256) {
                const int r = i / KF4, q = i % KF4;
                const float4 v = *(const float4*)((const float*)Am + (size_t)(m0 + r) * lda + k0 + q * 4);
                As[r][q * 4 + 0] = v.x; As[r][q * 4 + 1] = v.y;
                As[r][q * 4 + 2] = v.z; As[r][q * 4 + 3] = v.w;
            }
        } else {
            constexpr int KF8 = BK / 8;
            for (int i = tid; i < BM * KF8; i += 256) {
                const int r = i / KF8, q = i % KF8;
                const ushort8 v = *(const ushort8*)((const unsigned short*)Am + (size_t)(m0 + r) * lda + k0 + q * 8);
#pragma unroll
                for (int e = 0; e < 8; e++) As[r][q * 8 + e] = bf2f(v[e]);
            }
        }
        // ---- stage W tile (always f32) ----
        {
            constexpr int KF4 = BK / 4;
            for (int i = tid; i < BN * KF4; i += 256) {
                const int r = i / KF4, q = i % KF4;
                const float4 v = *(const float4*)(Wm + (size_t)(n0 + r) * K + k0 + q * 4);
                Ws[r][q * 4 + 0] = v.x; Ws[r][q * 4 + 1] = v.y;
                Ws[r][q * 4 + 2] = v.z; Ws[r][q * 4 + 3] = v.w;
            }
        }
        __syncthreads();
#pragma unroll
        for (int k = 0; k < BK; k++) {
            float ar[TM], wr[TN];
#pragma unroll
            for (int i = 0; i < TM; i++) ar[i] = As[ty * TM + i][k];
#pragma unroll
            for (int j = 0; j < TN; j++) wr[j] = Ws[tx * TN + j][k];
#pragma unroll
            for (int i = 0; i < TM; i++)
#pragma unroll
                for (int j = 0; j < TN; j++)
                    acc[i][j] += ar[i] * wr[j];
        }
        __syncthreads();
    }

    // ---- epilogue ----
#pragma unroll
    for (int i = 0; i < TM; i++) {
        const int row = m0 + ty * TM + i;
        const int col0 = n0 + tx * TN;
        float vout[TN];
#pragma unroll
        for (int j = 0; j < TN; j++) {
            float v = acc[i][j];
            if constexpr (ACT == 2) {
                const float bb = bias[col0 + j];
                v = softplus_f(softplus_f(v + bb) + bb);
            }
            vout[j] = v;
        }
        if constexpr (ACT == 1) {
            // bf16 split store; tile (BN=128) lies entirely in one half
            TO* dst = (col0 < D_INNER_) ? C0 : C1;
            const int c0 = (col0 < D_INNER_) ? col0 : col0 - D_INNER_;
            ushort8 vv;
#pragma unroll
            for (int j = 0; j < TN; j++) vv[j] = f2bf(vout[j]);
            *(ushort8*)((unsigned short*)dst + (size_t)row * D_INNER_ + c0) = vv;
        } else if constexpr (sizeof(TO) == 2) {
            ushort8 vv;
#pragma unroll
            for (int j = 0; j < TN; j++) vv[j] = f2bf(vout[j]);
            *(ushort8*)((unsigned short*)C0 + (size_t)row * N + col0) = vv;
        } else if constexpr (TN == 8) {
            float4 a, b;
            a.x = vout[0]; a.y = vout[1]; a.z = vout[2]; a.w = vout[3];
            b.x = vout[4]; b.y = vout[5]; b.z = vout[6]; b.w = vout[7];
            *(float4*)((float*)C0 + (size_t)row * N + col0) = a;
            *(float4*)((float*)C0 + (size_t)row * N + col0 + 4) = b;
        } else {
#pragma unroll
            for (int j = 0; j < TN; j++)
                ((float*)C0)[(size_t)row * N + col0 + j] = vout[j];
        }
    }
}

// conv_state[b][d][k] = u[b, L-4+k, d]  (u bf16 -> f32 out)
__global__ __launch_bounds__(256) void conv_state_kernel(
    const unsigned short* __restrict__ u, float* __restrict__ cs)
{
    const int idx = blockIdx.x * 256 + threadIdx.x;
    if (idx >= B_SZ * D_INNER_ * D_CONV_) return;
    const int k = idx % D_CONV_;
    const int d = (idx / D_CONV_) % D_INNER_;
    const int b = idx / (D_CONV_ * D_INNER_);
    cs[idx] = bf2f(u[((size_t)b * L_SZ + (L_SZ - D_CONV_ + k)) * D_INNER_ + d]);
}

// x[b,l,d] = silu(conv_b[d] + sum_k u[b, l-3+k, d] * conv_w[d,k]); 8 channels/thread
__global__ __launch_bounds__(256) void conv_silu_kernel(
    const unsigned short* __restrict__ u, const float* __restrict__ cw,
    const float* __restrict__ cb, unsigned short* __restrict__ x)
{
    constexpr int D8 = D_INNER_ / 8;
    const size_t total = (size_t)B_SZ * L_SZ * D8;
    const size_t idx = (size_t)blockIdx.x * 256 + threadIdx.x;
    if (idx >= total) return;
    const int d0 = (int)(idx % D8) * 8;
    const size_t bl = idx / D8;         // b*L + l
    const int l = (int)(bl % L_SZ);

    float accv[8];
#pragma unroll
    for (int e = 0; e < 8; e++) accv[e] = cb[d0 + e];

#pragma unroll
    for (int k = 0; k < 4; k++) {
        const int ls = l - 3 + k;
        if (ls >= 0) {
            const ushort8 v = *(const ushort8*)(u + (bl - 3 + k) * D_INNER_ + d0);
#pragma unroll
            for (int e = 0; e < 8; e++)
                accv[e] += bf2f(v[e]) * cw[(d0 + e) * 4 + k];
        }
    }
    ushort8 o;
#pragma unroll
    for (int e = 0; e < 8; e++) o[e] = f2bf(silu_f(accv[e]));
    *(ushort8*)(x + bl * D_INNER_ + d0) = o;
}

// Sequential selective scan: one thread per (b, d), 16 states in regs.
// y = (scan_y + x*D) * silu(z), written IN-PLACE over delta (y==delta allowed).
__global__ __launch_bounds__(64) void scan_kernel(
    const unsigned short* __restrict__ delta, const unsigned short* __restrict__ x,
    const float* __restrict__ xdbl, const unsigned short* __restrict__ z,
    const float* __restrict__ A_log, const float* __restrict__ Dv,
    unsigned short* __restrict__ y, float* __restrict__ last_state)
{
    const int d = blockIdx.x * 64 + threadIdx.x;
    const int b = blockIdx.y;

    float a[D_STATE_];
#pragma unroll
    for (int n = 0; n < D_STATE_; n++) a[n] = -expf(A_log[d * D_STATE_ + n]);
    const float Dd = Dv[d];

    float s[D_STATE_];
#pragma unroll
    for (int n = 0; n < D_STATE_; n++) s[n] = 0.f;

    const float* xr = xdbl + (size_t)b * L_SZ * 96;
    const size_t base = (size_t)b * L_SZ * D_INNER_ + d;

    // prefetch t = 0
    float4 Bq[4], Cq[4];
#pragma unroll
    for (int q = 0; q < 4; q++) {
        Bq[q] = *(const float4*)(xr + DT_RANK_ + q * 4);
        Cq[q] = *(const float4*)(xr + DT_RANK_ + D_STATE_ + q * 4);
    }
    float dlt = bf2f(delta[base]), xv = bf2f(x[base]), zv = bf2f(z[base]);

    for (int t = 0; t < L_SZ; t++) {
        // prefetch t+1 (clamped; last-iter values unused)
        const int tn = (t + 1 < L_SZ) ? (t + 1) : t;
        const float* rn = xr + (size_t)tn * 96;
        float4 Bqn[4], Cqn[4];
#pragma unroll
        for (int q = 0; q < 4; q++) {
            Bqn[q] = *(const float4*)(rn + DT_RANK_ + q * 4);
            Cqn[q] = *(const float4*)(rn + DT_RANK_ + D_STATE_ + q * 4);
        }
        const size_t basen = base + (size_t)tn * D_INNER_;
        const float dltn = bf2f(delta[basen]);
        const float xvn = bf2f(x[basen]);
        const float zvn = bf2f(z[basen]);

        // compute current step
        const float du = dlt * xv;
        const float* Bf = (const float*)Bq;
        const float* Cf = (const float*)Cq;
        float yv = 0.f;
#pragma unroll
        for (int n = 0; n < D_STATE_; n++) {
            s[n] = __expf(dlt * a[n]) * s[n] + du * Bf[n];
            yv += s[n] * Cf[n];
        }
        y[base + (size_t)t * D_INNER_] = f2bf((yv + xv * Dd) * silu_f(zv));

#pragma unroll
        for (int q = 0; q < 4; q++) { Bq[q] = Bqn[q]; Cq[q] = Cqn[q]; }
        dlt = dltn; xv = xvn; zv = zvn;
    }

#pragma unroll
    for (int n = 0; n < D_STATE_; n++)
        last_state[((size_t)b * D_INNER_ + d) * D_STATE_ + n] = s[n];
}

extern "C" void kernel_launch(void* const* d_in, const int* in_sizes, int n_in,
                              void* d_out, int out_size, void* d_ws, size_t ws_size,
                              hipStream_t stream) {
    const float* hidden     = (const float*)d_in[0];
    const float* in_proj_w  = (const float*)d_in[1];
    const float* conv_w     = (const float*)d_in[2];
    const float* conv_b     = (const float*)d_in[3];
    const float* x_proj_w   = (const float*)d_in[4];
    const float* dt_proj_w  = (const float*)d_in[5];
    const float* dt_proj_b  = (const float*)d_in[6];
    const float* A_log      = (const float*)d_in[7];
    const float* Dvec       = (const float*)d_in[8];
    const float* out_proj_w = (const float*)d_in[9];

    const size_t NT = (size_t)B_SZ * L_SZ * D_INNER_;   // 16,777,216 elems
    // Workspace layout (bf16 intermediates):
    //   r0 [0,      32MiB) : u  -> delta -> y   (in-place reuse)
    //   r1 [32MiB,  64MiB) : x
    //   r2 [64MiB, ~67MiB) : xdbl f32 (8192 x 96)
    const size_t required = NT * 2 * 2 + (size_t)B_SZ * L_SZ * 96 * 4;  // 70,254,592 B
    if (ws_size < required) return;  // clean fail -> diagnosable, no heap corruption

    char* wsb = (char*)d_ws;
    unsigned short* r0   = (unsigned short*)wsb;                    // u / delta / y
    unsigned short* xb   = (unsigned short*)(wsb + NT * 2);         // x
    float*          xdbl = (float*)(wsb + NT * 4);                  // x_dbl

    // z lives in d_out's out-region (exactly B*L*D_MODEL f32 = NT bf16),
    // dead before the final GEMM overwrites it with the real output.
    float* out = (float*)d_out;
    unsigned short* zb = (unsigned short*)d_out;
    float* conv_state_out = out + (size_t)B_SZ * L_SZ * D_MODEL_;
    float* last_state_out = conv_state_out + (size_t)B_SZ * D_INNER_ * D_CONV_;

    const int M = B_SZ * L_SZ;  // 8192
    dim3 blk(256);

    // 1) in_proj: [u | z] = hidden @ in_proj_w^T  (u -> r0, z -> d_out region)
    gemm_t<float, unsigned short, 128, 128, 16, 8, 8, 1>
        <<<dim3((2 * D_INNER_) / 128, M / 128), blk, 0, stream>>>(
        hidden, D_MODEL_, in_proj_w, nullptr, r0, zb, M, 2 * D_INNER_, D_MODEL_);

    // 2) conv_state output (reads u)
    conv_state_kernel<<<(B_SZ * D_INNER_ * D_CONV_ + 255) / 256, blk, 0, stream>>>(
        r0, conv_state_out);

    // 3) depthwise causal conv + SiLU: u -> x
    conv_silu_kernel<<<(B_SZ * L_SZ * (D_INNER_ / 8) + 255) / 256, blk, 0, stream>>>(
        r0, conv_w, conv_b, xb);

    // 4) x_dbl = x @ x_proj_w^T  (N = 96, f32 out)
    gemm_t<unsigned short, float, 64, 96, 16, 4, 6, 0>
        <<<dim3(1, M / 64), blk, 0, stream>>>(
        xb, D_INNER_, x_proj_w, nullptr, xdbl, nullptr, M, 96, D_INNER_);

    // 5) delta = softplus(softplus(ts @ dt_proj_w^T + b) + b) -> r0 (u is dead)
    gemm_t<float, unsigned short, 128, 128, 16, 8, 8, 2>
        <<<dim3(D_INNER_ / 128, M / 128), blk, 0, stream>>>(
        xdbl, 96, dt_proj_w, dt_proj_b, r0, nullptr, M, D_INNER_, DT_RANK_);

    // 6) selective scan + gating epilogue: y in-place over delta (r0)
    scan_kernel<<<dim3(D_INNER_ / 64, B_SZ), dim3(64), 0, stream>>>(
        r0, xb, xdbl, zb, A_log, Dvec, r0, last_state_out);

    // 7) out = y @ out_proj_w^T  (overwrites z region with final output)
    gemm_t<unsigned short, float, 128, 128, 16, 8, 8, 0>
        <<<dim3(D_MODEL_ / 128, M / 128), blk, 0, stream>>>(
        r0, D_INNER_, out_proj_w, nullptr, out, nullptr, M, D_MODEL_, D_INNER_);
}

// Round 4
// 2644.422 us; speedup vs baseline: 1.7523x; 1.7523x over previous
//
#include <hip/hip_runtime.h>
#include <hip/hip_bf16.h>
#include <math.h>

#define B_SZ 2
#define L_SZ 4096
#define D_MODEL_ 1024
#define D_INNER_ 2048
#define D_STATE_ 16
#define D_CONV_ 4
#define DT_RANK_ 64
#define NCHUNK 32
#define CLEN 128   // NCHUNK * CLEN == L_SZ

typedef unsigned short ushort8 __attribute__((ext_vector_type(8)));

__device__ __forceinline__ float bf2f(unsigned short b) {
    return __uint_as_float(((unsigned)b) << 16);
}
__device__ __forceinline__ unsigned short f2bf(float f) {
    unsigned u = __float_as_uint(f);
    unsigned r = (u + 0x7fffu + ((u >> 16) & 1u)) >> 16;  // RNE
    return (unsigned short)r;
}
__device__ __forceinline__ float softplus_f(float x) {
    return (x > 20.f) ? x : log1pf(__expf(x));
}
__device__ __forceinline__ float silu_f(float x) {
    return x / (1.f + __expf(-x));
}

// Tiled GEMM: C = act(A[M,K(lda)] @ W[N,K]^T), f32 accumulate in VALU.
// ACT 0: plain write. ACT 1: split cols at D_INNER -> C0/C1 (bf16).
// ACT 2: softplus(softplus(v + bias) + bias)
template<typename TA, typename TO, int BM, int BN, int BK, int TM, int TN, int ACT>
__global__ __launch_bounds__(256) void gemm_t(
    const TA* __restrict__ Am, int lda,
    const float* __restrict__ Wm,
    const float* __restrict__ bias,
    TO* __restrict__ C0, TO* __restrict__ C1,
    int M, int N, int K)
{
    constexpr int TX = BN / TN;
    constexpr int TY = BM / TM;
    static_assert(TX * TY == 256, "bad tiling");
    __shared__ float As[BM][BK + 1];
    __shared__ float Ws[BN][BK + 1];
    const int tid = threadIdx.x;
    const int tx = tid % TX, ty = tid / TX;
    const int m0 = blockIdx.y * BM;
    const int n0 = blockIdx.x * BN;

    float acc[TM][TN];
#pragma unroll
    for (int i = 0; i < TM; i++)
#pragma unroll
        for (int j = 0; j < TN; j++) acc[i][j] = 0.f;

    for (int k0 = 0; k0 < K; k0 += BK) {
        if constexpr (sizeof(TA) == 4) {
            constexpr int KF4 = BK / 4;
            for (int i = tid; i < BM * KF4; i += 256) {
                const int r = i / KF4, q = i % KF4;
                const float4 v = *(const float4*)((const float*)Am + (size_t)(m0 + r) * lda + k0 + q * 4);
                As[r][q * 4 + 0] = v.x; As[r][q * 4 + 1] = v.y;
                As[r][q * 4 + 2] = v.z; As[r][q * 4 + 3] = v.w;
            }
        } else {
            constexpr int KF8 = BK / 8;
            for (int i = tid; i < BM * KF8; i += 256) {
                const int r = i / KF8, q = i % KF8;
                const ushort8 v = *(const ushort8*)((const unsigned short*)Am + (size_t)(m0 + r) * lda + k0 + q * 8);
#pragma unroll
                for (int e = 0; e < 8; e++) As[r][q * 8 + e] = bf2f(v[e]);
            }
        }
        {
            constexpr int KF4 = BK / 4;
            for (int i = tid; i < BN * KF4; i += 256) {
                const int r = i / KF4, q = i % KF4;
                const float4 v = *(const float4*)(Wm + (size_t)(n0 + r) * K + k0 + q * 4);
                Ws[r][q * 4 + 0] = v.x; Ws[r][q * 4 + 1] = v.y;
                Ws[r][q * 4 + 2] = v.z; Ws[r][q * 4 + 3] = v.w;
            }
        }
        __syncthreads();
#pragma unroll
        for (int k = 0; k < BK; k++) {
            float ar[TM], wr[TN];
#pragma unroll
            for (int i = 0; i < TM; i++) ar[i] = As[ty * TM + i][k];
#pragma unroll
            for (int j = 0; j < TN; j++) wr[j] = Ws[tx * TN + j][k];
#pragma unroll
            for (int i = 0; i < TM; i++)
#pragma unroll
                for (int j = 0; j < TN; j++)
                    acc[i][j] += ar[i] * wr[j];
        }
        __syncthreads();
    }

#pragma unroll
    for (int i = 0; i < TM; i++) {
        const int row = m0 + ty * TM + i;
        const int col0 = n0 + tx * TN;
        float vout[TN];
#pragma unroll
        for (int j = 0; j < TN; j++) {
            float v = acc[i][j];
            if constexpr (ACT == 2) {
                const float bb = bias[col0 + j];
                v = softplus_f(softplus_f(v + bb) + bb);
            }
            vout[j] = v;
        }
        if constexpr (ACT == 1) {
            TO* dst = (col0 < D_INNER_) ? C0 : C1;
            const int c0 = (col0 < D_INNER_) ? col0 : col0 - D_INNER_;
            ushort8 vv;
#pragma unroll
            for (int j = 0; j < TN; j++) vv[j] = f2bf(vout[j]);
            *(ushort8*)((unsigned short*)dst + (size_t)row * D_INNER_ + c0) = vv;
        } else if constexpr (sizeof(TO) == 2) {
            ushort8 vv;
#pragma unroll
            for (int j = 0; j < TN; j++) vv[j] = f2bf(vout[j]);
            *(ushort8*)((unsigned short*)C0 + (size_t)row * N + col0) = vv;
        } else if constexpr (TN == 8) {
            float4 a, b;
            a.x = vout[0]; a.y = vout[1]; a.z = vout[2]; a.w = vout[3];
            b.x = vout[4]; b.y = vout[5]; b.z = vout[6]; b.w = vout[7];
            *(float4*)((float*)C0 + (size_t)row * N + col0) = a;
            *(float4*)((float*)C0 + (size_t)row * N + col0 + 4) = b;
        } else {
#pragma unroll
            for (int j = 0; j < TN; j++)
                ((float*)C0)[(size_t)row * N + col0 + j] = vout[j];
        }
    }
}

// conv_state[b][d][k] = u[b, L-4+k, d]  (u bf16 -> f32 out)
__global__ __launch_bounds__(256) void conv_state_kernel(
    const unsigned short* __restrict__ u, float* __restrict__ cs)
{
    const int idx = blockIdx.x * 256 + threadIdx.x;
    if (idx >= B_SZ * D_INNER_ * D_CONV_) return;
    const int k = idx % D_CONV_;
    const int d = (idx / D_CONV_) % D_INNER_;
    const int b = idx / (D_CONV_ * D_INNER_);
    cs[idx] = bf2f(u[((size_t)b * L_SZ + (L_SZ - D_CONV_ + k)) * D_INNER_ + d]);
}

// x[b,l,d] = silu(conv_b[d] + sum_k u[b, l-3+k, d] * conv_w[d,k]); 8 channels/thread
__global__ __launch_bounds__(256) void conv_silu_kernel(
    const unsigned short* __restrict__ u, const float* __restrict__ cw,
    const float* __restrict__ cb, unsigned short* __restrict__ x)
{
    constexpr int D8 = D_INNER_ / 8;
    const size_t total = (size_t)B_SZ * L_SZ * D8;
    const size_t idx = (size_t)blockIdx.x * 256 + threadIdx.x;
    if (idx >= total) return;
    const int d0 = (int)(idx % D8) * 8;
    const size_t bl = idx / D8;
    const int l = (int)(bl % L_SZ);

    float accv[8];
#pragma unroll
    for (int e = 0; e < 8; e++) accv[e] = cb[d0 + e];

#pragma unroll
    for (int k = 0; k < 4; k++) {
        const int ls = l - 3 + k;
        if (ls >= 0) {
            const ushort8 v = *(const ushort8*)(u + (bl - 3 + k) * D_INNER_ + d0);
#pragma unroll
            for (int e = 0; e < 8; e++)
                accv[e] += bf2f(v[e]) * cw[(d0 + e) * 4 + k];
        }
    }
    ushort8 o;
#pragma unroll
    for (int e = 0; e < 8; e++) o[e] = f2bf(silu_f(accv[e]));
    *(ushort8*)(x + bl * D_INNER_ + d0) = o;
}

// ---------------- chunk-parallel scan ----------------
// pass1: per (b,d,chunk) local scan from zero state. Stores h[16] and sum(delta).
__global__ __launch_bounds__(256) void scan_pass1(
    const unsigned short* __restrict__ delta, const unsigned short* __restrict__ x,
    const float* __restrict__ xdbl, const float* __restrict__ A_log,
    float* __restrict__ H, float* __restrict__ S)
{
    const int d = blockIdx.x * 256 + threadIdx.x;   // 0..2047
    const int c = blockIdx.y;
    const int b = blockIdx.z;

    float a[D_STATE_];
#pragma unroll
    for (int n = 0; n < D_STATE_; n++) a[n] = -expf(A_log[d * D_STATE_ + n]);

    float s[D_STATE_];
#pragma unroll
    for (int n = 0; n < D_STATE_; n++) s[n] = 0.f;
    float sum = 0.f;

    const int t0 = c * CLEN;
    const float* xr = xdbl + ((size_t)b * L_SZ + t0) * 96;
    size_t base = ((size_t)b * L_SZ + t0) * D_INNER_ + d;

    for (int t = 0; t < CLEN; t++) {
        const float dlt = bf2f(delta[base]);
        const float xv  = bf2f(x[base]);
        float4 Bq[4];
#pragma unroll
        for (int q = 0; q < 4; q++) Bq[q] = *(const float4*)(xr + DT_RANK_ + q * 4);
        const float* Bf = (const float*)Bq;
        const float du = dlt * xv;
        sum += dlt;
#pragma unroll
        for (int n = 0; n < D_STATE_; n++)
            s[n] = __expf(dlt * a[n]) * s[n] + du * Bf[n];
        base += D_INNER_;
        xr += 96;
    }

    float* Hp = H + (((size_t)b * NCHUNK + c) * D_INNER_ + d) * D_STATE_;
#pragma unroll
    for (int q = 0; q < 4; q++)
        *(float4*)(Hp + q * 4) = make_float4(s[q*4], s[q*4+1], s[q*4+2], s[q*4+3]);
    S[((size_t)b * NCHUNK + c) * D_INNER_ + d] = sum;
}

// combine: per chain, fold chunks sequentially; H[c] <- carry_c (in place); emit last_state.
__global__ __launch_bounds__(256) void scan_combine(
    const float* __restrict__ A_log, float* __restrict__ H,
    const float* __restrict__ S, float* __restrict__ last_state)
{
    const int idx = blockIdx.x * 256 + threadIdx.x;  // 0..4095
    const int d = idx & (D_INNER_ - 1);
    const int b = idx >> 11;

    float a[D_STATE_];
#pragma unroll
    for (int n = 0; n < D_STATE_; n++) a[n] = -expf(A_log[d * D_STATE_ + n]);

    float cur[D_STATE_];
#pragma unroll
    for (int n = 0; n < D_STATE_; n++) cur[n] = 0.f;

    for (int c = 0; c < NCHUNK; c++) {
        float* Hp = H + (((size_t)b * NCHUNK + c) * D_INNER_ + d) * D_STATE_;
        const float Sv = S[((size_t)b * NCHUNK + c) * D_INNER_ + d];
        float h[D_STATE_];
#pragma unroll
        for (int q = 0; q < 4; q++) {
            const float4 v = *(const float4*)(Hp + q * 4);
            h[q*4] = v.x; h[q*4+1] = v.y; h[q*4+2] = v.z; h[q*4+3] = v.w;
        }
        float nxt[D_STATE_];
#pragma unroll
        for (int n = 0; n < D_STATE_; n++)
            nxt[n] = h[n] + __expf(a[n] * Sv) * cur[n];
        // write carry_c over h_c
#pragma unroll
        for (int q = 0; q < 4; q++)
            *(float4*)(Hp + q * 4) = make_float4(cur[q*4], cur[q*4+1], cur[q*4+2], cur[q*4+3]);
#pragma unroll
        for (int n = 0; n < D_STATE_; n++) cur[n] = nxt[n];
    }
#pragma unroll
    for (int n = 0; n < D_STATE_; n++)
        last_state[((size_t)b * D_INNER_ + d) * D_STATE_ + n] = cur[n];
}

// pass3: re-run chunk seeded with carry; fused y = (scan_y + x*D) * silu(z),
// written in place over delta (same-thread, same-element, after consumption).
__global__ __launch_bounds__(256) void scan_pass3(
    const unsigned short* __restrict__ delta, const unsigned short* __restrict__ x,
    const float* __restrict__ xdbl, const unsigned short* __restrict__ z,
    const float* __restrict__ A_log, const float* __restrict__ Dv,
    const float* __restrict__ H, unsigned short* __restrict__ y)
{
    const int d = blockIdx.x * 256 + threadIdx.x;
    const int c = blockIdx.y;
    const int b = blockIdx.z;

    float a[D_STATE_];
#pragma unroll
    for (int n = 0; n < D_STATE_; n++) a[n] = -expf(A_log[d * D_STATE_ + n]);
    const float Dd = Dv[d];

    const float* Hp = H + (((size_t)b * NCHUNK + c) * D_INNER_ + d) * D_STATE_;
    float s[D_STATE_];
#pragma unroll
    for (int q = 0; q < 4; q++) {
        const float4 v = *(const float4*)(Hp + q * 4);
        s[q*4] = v.x; s[q*4+1] = v.y; s[q*4+2] = v.z; s[q*4+3] = v.w;
    }

    const int t0 = c * CLEN;
    const float* xr = xdbl + ((size_t)b * L_SZ + t0) * 96;
    size_t base = ((size_t)b * L_SZ + t0) * D_INNER_ + d;

    for (int t = 0; t < CLEN; t++) {
        const float dlt = bf2f(delta[base]);
        const float xv  = bf2f(x[base]);
        const float zv  = bf2f(z[base]);
        float4 Bq[4], Cq[4];
#pragma unroll
        for (int q = 0; q < 4; q++) {
            Bq[q] = *(const float4*)(xr + DT_RANK_ + q * 4);
            Cq[q] = *(const float4*)(xr + DT_RANK_ + D_STATE_ + q * 4);
        }
        const float* Bf = (const float*)Bq;
        const float* Cf = (const float*)Cq;
        const float du = dlt * xv;
        float yv = 0.f;
#pragma unroll
        for (int n = 0; n < D_STATE_; n++) {
            s[n] = __expf(dlt * a[n]) * s[n] + du * Bf[n];
            yv += s[n] * Cf[n];
        }
        y[base] = f2bf((yv + xv * Dd) * silu_f(zv));
        base += D_INNER_;
        xr += 96;
    }
}

// ---------------- fallback sequential scan (known-good, R3) ----------------
__global__ __launch_bounds__(64) void scan_kernel(
    const unsigned short* __restrict__ delta, const unsigned short* __restrict__ x,
    const float* __restrict__ xdbl, const unsigned short* __restrict__ z,
    const float* __restrict__ A_log, const float* __restrict__ Dv,
    unsigned short* __restrict__ y, float* __restrict__ last_state)
{
    const int d = blockIdx.x * 64 + threadIdx.x;
    const int b = blockIdx.y;

    float a[D_STATE_];
#pragma unroll
    for (int n = 0; n < D_STATE_; n++) a[n] = -expf(A_log[d * D_STATE_ + n]);
    const float Dd = Dv[d];

    float s[D_STATE_];
#pragma unroll
    for (int n = 0; n < D_STATE_; n++) s[n] = 0.f;

    const float* xr = xdbl + (size_t)b * L_SZ * 96;
    const size_t base = (size_t)b * L_SZ * D_INNER_ + d;

    float4 Bq[4], Cq[4];
#pragma unroll
    for (int q = 0; q < 4; q++) {
        Bq[q] = *(const float4*)(xr + DT_RANK_ + q * 4);
        Cq[q] = *(const float4*)(xr + DT_RANK_ + D_STATE_ + q * 4);
    }
    float dlt = bf2f(delta[base]), xv = bf2f(x[base]), zv = bf2f(z[base]);

    for (int t = 0; t < L_SZ; t++) {
        const int tn = (t + 1 < L_SZ) ? (t + 1) : t;
        const float* rn = xr + (size_t)tn * 96;
        float4 Bqn[4], Cqn[4];
#pragma unroll
        for (int q = 0; q < 4; q++) {
            Bqn[q] = *(const float4*)(rn + DT_RANK_ + q * 4);
            Cqn[q] = *(const float4*)(rn + DT_RANK_ + D_STATE_ + q * 4);
        }
        const size_t basen = base + (size_t)tn * D_INNER_;
        const float dltn = bf2f(delta[basen]);
        const float xvn = bf2f(x[basen]);
        const float zvn = bf2f(z[basen]);

        const float du = dlt * xv;
        const float* Bf = (const float*)Bq;
        const float* Cf = (const float*)Cq;
        float yv = 0.f;
#pragma unroll
        for (int n = 0; n < D_STATE_; n++) {
            s[n] = __expf(dlt * a[n]) * s[n] + du * Bf[n];
            yv += s[n] * Cf[n];
        }
        y[base + (size_t)t * D_INNER_] = f2bf((yv + xv * Dd) * silu_f(zv));

#pragma unroll
        for (int q = 0; q < 4; q++) { Bq[q] = Bqn[q]; Cq[q] = Cqn[q]; }
        dlt = dltn; xv = xvn; zv = zvn;
    }

#pragma unroll
    for (int n = 0; n < D_STATE_; n++)
        last_state[((size_t)b * D_INNER_ + d) * D_STATE_ + n] = s[n];
}

extern "C" void kernel_launch(void* const* d_in, const int* in_sizes, int n_in,
                              void* d_out, int out_size, void* d_ws, size_t ws_size,
                              hipStream_t stream) {
    const float* hidden     = (const float*)d_in[0];
    const float* in_proj_w  = (const float*)d_in[1];
    const float* conv_w     = (const float*)d_in[2];
    const float* conv_b     = (const float*)d_in[3];
    const float* x_proj_w   = (const float*)d_in[4];
    const float* dt_proj_w  = (const float*)d_in[5];
    const float* dt_proj_b  = (const float*)d_in[6];
    const float* A_log      = (const float*)d_in[7];
    const float* Dvec       = (const float*)d_in[8];
    const float* out_proj_w = (const float*)d_in[9];

    const size_t NT = (size_t)B_SZ * L_SZ * D_INNER_;   // 16,777,216 elems
    // ws layout:
    //   r0   [0,        NT*2)      : u -> delta -> y  (bf16, in-place reuse)
    //   xb   [NT*2,     NT*4)      : x (bf16)
    //   xdbl [NT*4,     +3.1MB)    : x_dbl f32 (8192 x 96)
    //   H    [...,      +8.39MB)   : chunk h / carry  (f32, [b][c][d][16])
    //   S    [...,      +0.52MB)   : chunk sum(delta) (f32, [b][c][d])
    const size_t off_xdbl = NT * 4;
    const size_t off_H    = off_xdbl + (size_t)B_SZ * L_SZ * 96 * 4;
    const size_t off_S    = off_H + (size_t)B_SZ * NCHUNK * D_INNER_ * D_STATE_ * 4;
    const size_t req_seq     = off_H;                                        // 70,254,592
    const size_t req_chunked = off_S + (size_t)B_SZ * NCHUNK * D_INNER_ * 4; // 79,167,488
    if (ws_size < req_seq) return;

    char* wsb = (char*)d_ws;
    unsigned short* r0   = (unsigned short*)wsb;
    unsigned short* xb   = (unsigned short*)(wsb + NT * 2);
    float*          xdbl = (float*)(wsb + off_xdbl);
    float*          Hbuf = (float*)(wsb + off_H);
    float*          Sbuf = (float*)(wsb + off_S);

    float* out = (float*)d_out;
    unsigned short* zb = (unsigned short*)d_out;  // z parked in out region (dead before final GEMM)
    float* conv_state_out = out + (size_t)B_SZ * L_SZ * D_MODEL_;
    float* last_state_out = conv_state_out + (size_t)B_SZ * D_INNER_ * D_CONV_;

    const int M = B_SZ * L_SZ;  // 8192
    dim3 blk(256);

    // 1) in_proj: [u | z] = hidden @ in_proj_w^T
    gemm_t<float, unsigned short, 128, 128, 16, 8, 8, 1>
        <<<dim3((2 * D_INNER_) / 128, M / 128), blk, 0, stream>>>(
        hidden, D_MODEL_, in_proj_w, nullptr, r0, zb, M, 2 * D_INNER_, D_MODEL_);

    // 2) conv_state output
    conv_state_kernel<<<(B_SZ * D_INNER_ * D_CONV_ + 255) / 256, blk, 0, stream>>>(
        r0, conv_state_out);

    // 3) depthwise causal conv + SiLU: u -> x
    conv_silu_kernel<<<(B_SZ * L_SZ * (D_INNER_ / 8) + 255) / 256, blk, 0, stream>>>(
        r0, conv_w, conv_b, xb);

    // 4) x_dbl = x @ x_proj_w^T
    gemm_t<unsigned short, float, 64, 96, 16, 4, 6, 0>
        <<<dim3(1, M / 64), blk, 0, stream>>>(
        xb, D_INNER_, x_proj_w, nullptr, xdbl, nullptr, M, 96, D_INNER_);

    // 5) delta = softplus(softplus(ts @ dt_proj_w^T + b) + b) -> r0
    gemm_t<float, unsigned short, 128, 128, 16, 8, 8, 2>
        <<<dim3(D_INNER_ / 128, M / 128), blk, 0, stream>>>(
        xdbl, 96, dt_proj_w, dt_proj_b, r0, nullptr, M, D_INNER_, DT_RANK_);

    // 6) selective scan
    if (ws_size >= req_chunked) {
        dim3 g13(D_INNER_ / 256, NCHUNK, B_SZ);
        scan_pass1<<<g13, blk, 0, stream>>>(r0, xb, xdbl, A_log, Hbuf, Sbuf);
        scan_combine<<<(B_SZ * D_INNER_) / 256, blk, 0, stream>>>(
            A_log, Hbuf, Sbuf, last_state_out);
        scan_pass3<<<g13, blk, 0, stream>>>(r0, xb, xdbl, zb, A_log, Dvec, Hbuf, r0);
    } else {
        scan_kernel<<<dim3(D_INNER_ / 64, B_SZ), dim3(64), 0, stream>>>(
            r0, xb, xdbl, zb, A_log, Dvec, r0, last_state_out);
    }

    // 7) out = y @ out_proj_w^T
    gemm_t<unsigned short, float, 128, 128, 16, 8, 8, 0>
        <<<dim3(D_MODEL_ / 128, M / 128), blk, 0, stream>>>(
        r0, D_INNER_, out_proj_w, nullptr, out, nullptr, M, D_MODEL_, D_INNER_);
}

// Round 6
// 922.942 us; speedup vs baseline: 5.0206x; 2.8652x over previous
//
#include <hip/hip_runtime.h>
#include <hip/hip_bf16.h>
#include <math.h>

#define B_SZ 2
#define L_SZ 4096
#define D_MODEL_ 1024
#define D_INNER_ 2048
#define D_STATE_ 16
#define D_CONV_ 4
#define DT_RANK_ 64
#define NCHUNK 32
#define CLEN 128   // NCHUNK * CLEN == L_SZ

typedef unsigned short ushort8 __attribute__((ext_vector_type(8)));
typedef unsigned short ushort4v __attribute__((ext_vector_type(4)));
typedef short mfrag8 __attribute__((ext_vector_type(8)));   // 8 bf16 (4 VGPR) MFMA A/B frag
typedef float facc4 __attribute__((ext_vector_type(4)));    // 4 f32 MFMA C/D frag

__device__ __forceinline__ float bf2f(unsigned short b) {
    return __uint_as_float(((unsigned)b) << 16);
}
__device__ __forceinline__ unsigned short f2bf(float f) {
    unsigned u = __float_as_uint(f);
    unsigned r = (u + 0x7fffu + ((u >> 16) & 1u)) >> 16;  // RNE
    return (unsigned short)r;
}
__device__ __forceinline__ float softplus_f(float x) {
    return (x > 20.f) ? x : log1pf(__expf(x));
}
__device__ __forceinline__ float silu_f(float x) {
    return x / (1.f + __expf(-x));
}
// async global -> LDS, 16B per lane (wave-uniform LDS base, per-lane global src)
__device__ __forceinline__ void gload_lds16(const void* g, void* l) {
    __builtin_amdgcn_global_load_lds(
        (const __attribute__((address_space(1))) unsigned int*)g,
        (__attribute__((address_space(3))) unsigned int*)l,
        16, 0, 0);
}

// ---------------------------------------------------------------------------
// f32 -> bf16 convert (vectorized)
__global__ __launch_bounds__(256) void f32_to_bf16_kernel(
    const float* __restrict__ in, unsigned short* __restrict__ out, int n4)
{
    for (size_t i = (size_t)blockIdx.x * 256 + threadIdx.x; i < (size_t)n4;
         i += (size_t)gridDim.x * 256) {
        const float4 v = *(const float4*)(in + i * 4);
        ushort4v o;
        o[0] = f2bf(v.x); o[1] = f2bf(v.y); o[2] = f2bf(v.z); o[3] = f2bf(v.w);
        *(ushort4v*)(out + i * 4) = o;
    }
}

// ---------------------------------------------------------------------------
// MFMA bf16 GEMM: C[M,N] = A[M,K] @ W[N,K]^T
// 128x128 tile, BK=32, 4 waves (2x2), each wave 64x64 via 4x4 16x16x32 frags.
// global_load_lds(16B) staging, double-buffered LDS, 2-way-free bank swizzle
// (slot ^= (row>>1)&3) applied on the GLOBAL source (LDS dest stays linear).
// ACT 0: f32 out to Cf[M,N].  ACT 1: bf16 split at D_INNER_ -> U0 | U1.
template<int ACT>
__global__ __launch_bounds__(256) void gemm_mfma(
    const unsigned short* __restrict__ A,   // [M,K] bf16
    const unsigned short* __restrict__ W,   // [N,K] bf16
    float* __restrict__ Cf,
    unsigned short* __restrict__ U0, unsigned short* __restrict__ U1,
    int M, int N, int K)
{
    constexpr int BK = 32;
    __shared__ __align__(16) char lds[2 * 16384];  // [buf][A 8KB | W 8KB]

    const int tid = threadIdx.x;
    const int l   = tid & 63;
    const int wid = tid >> 6;   // 0..3
    const int wm  = wid >> 1;   // 0..1 (m half)
    const int wn  = wid & 1;    // 0..1 (n half)

    // XCD-aware block swizzle (nwg % 8 == 0 for all our grids)
    const int nwg  = gridDim.x * gridDim.y;
    const int flat = blockIdx.y * gridDim.x + blockIdx.x;
    const int swz  = (flat & 7) * (nwg >> 3) + (flat >> 3);
    const int m0   = (swz / gridDim.x) * 128;
    const int n0   = (swz % gridDim.x) * 128;

    // ---- staging: lane covers LDS (row = base + l/4, slot = l&3) ----
    const int rl   = l >> 2;
    const int slot = l & 3;
    const int xsl  = slot ^ ((rl >> 1) & 3);   // inverse swizzle on global source
    const char* a_src[2];
    const char* w_src[2];
#pragma unroll
    for (int i = 0; i < 2; i++) {
        const int r = wid * 32 + i * 16 + rl;          // row in tile
        a_src[i] = (const char*)A + ((size_t)(m0 + r) * K) * 2 + xsl * 16;
        w_src[i] = (const char*)W + ((size_t)(n0 + r) * K) * 2 + xsl * 16;
    }
    const int stg_off = wid * 32 * 64;  // wave's LDS byte offset (uniform per wave)

    // ---- ds_read fragment offsets: LDS[row][kg ^ s(row)] ----
    const int srow = l & 15;
    const int kg   = l >> 4;
    const int lo   = srow * 64 + (kg ^ ((srow >> 1) & 3)) * 16;
    int a_off[4], b_off[4];
#pragma unroll
    for (int i = 0; i < 4; i++) {
        a_off[i] = (wm * 64 + i * 16) * 64 + lo;
        b_off[i] = (wn * 64 + i * 16) * 64 + lo;
    }

    const facc4 zf = {0.f, 0.f, 0.f, 0.f};
    facc4 acc[4][4];
#pragma unroll
    for (int i = 0; i < 4; i++)
#pragma unroll
        for (int j = 0; j < 4; j++) acc[i][j] = zf;

    const int KT = K / BK;

    // prologue: stage tile 0 into buf 0
#pragma unroll
    for (int i = 0; i < 2; i++) {
        gload_lds16(a_src[i], lds + stg_off + i * 1024);
        gload_lds16(w_src[i], lds + 8192 + stg_off + i * 1024);
    }

    int cur = 0;
    for (int kt = 0; kt < KT; ++kt) {
        __syncthreads();   // buf[cur] staged; all waves done reading buf[cur^1]
        if (kt + 1 < KT) {
            const int koff = (kt + 1) * BK * 2;   // bytes
            char* dstA = lds + (cur ^ 1) * 16384 + stg_off;
#pragma unroll
            for (int i = 0; i < 2; i++) {
                gload_lds16(a_src[i] + koff, dstA + i * 1024);
                gload_lds16(w_src[i] + koff, dstA + 8192 + i * 1024);
            }
        }
        const char* base = lds + cur * 16384;
        mfrag8 af[4], bfr[4];
#pragma unroll
        for (int i = 0; i < 4; i++) af[i]  = *(const mfrag8*)(base + a_off[i]);
#pragma unroll
        for (int i = 0; i < 4; i++) bfr[i] = *(const mfrag8*)(base + 8192 + b_off[i]);
#pragma unroll
        for (int i = 0; i < 4; i++)
#pragma unroll
            for (int j = 0; j < 4; j++)
                acc[i][j] = __builtin_amdgcn_mfma_f32_16x16x32_bf16(af[i], bfr[j], acc[i][j], 0, 0, 0);
        cur ^= 1;
    }

    // epilogue: D[row = (l>>4)*4 + rr][col = l&15] per fragment (verified m89/m91)
    const int crow = (l >> 4) * 4;
    const int ccol = l & 15;
#pragma unroll
    for (int mi = 0; mi < 4; mi++) {
#pragma unroll
        for (int ni = 0; ni < 4; ni++) {
            const int col = n0 + wn * 64 + ni * 16 + ccol;
            const facc4 v = acc[mi][ni];
#pragma unroll
            for (int rr = 0; rr < 4; rr++) {
                const int row = m0 + wm * 64 + mi * 16 + crow + rr;
                if constexpr (ACT == 0) {
                    Cf[(size_t)row * N + col] = v[rr];
                } else {
                    if (col < D_INNER_)
                        U0[(size_t)row * D_INNER_ + col] = f2bf(v[rr]);
                    else
                        U1[(size_t)row * D_INNER_ + (col - D_INNER_)] = f2bf(v[rr]);
                }
            }
        }
    }
}

// ---------------------------------------------------------------------------
// f32-VALU tiled GEMM (kept for the small/skinny GEMMs)
// ACT 0: plain write. ACT 2: softplus(softplus(v + bias) + bias)
template<typename TA, typename TO, int BM, int BN, int BK, int TM, int TN, int ACT>
__global__ __launch_bounds__(256) void gemm_t(
    const TA* __restrict__ Am, int lda,
    const float* __restrict__ Wm,
    const float* __restrict__ bias,
    TO* __restrict__ C0,
    int M, int N, int K)
{
    constexpr int TX = BN / TN;
    constexpr int TY = BM / TM;
    static_assert(TX * TY == 256, "bad tiling");
    __shared__ float As[BM][BK + 1];
    __shared__ float Ws[BN][BK + 1];
    const int tid = threadIdx.x;
    const int tx = tid % TX, ty = tid / TX;
    const int m0 = blockIdx.y * BM;
    const int n0 = blockIdx.x * BN;

    float acc[TM][TN];
#pragma unroll
    for (int i = 0; i < TM; i++)
#pragma unroll
        for (int j = 0; j < TN; j++) acc[i][j] = 0.f;

    for (int k0 = 0; k0 < K; k0 += BK) {
        if constexpr (sizeof(TA) == 4) {
            constexpr int KF4 = BK / 4;
            for (int i = tid; i < BM * KF4; i += 256) {
                const int r = i / KF4, q = i % KF4;
                const float4 v = *(const float4*)((const float*)Am + (size_t)(m0 + r) * lda + k0 + q * 4);
                As[r][q * 4 + 0] = v.x; As[r][q * 4 + 1] = v.y;
                As[r][q * 4 + 2] = v.z; As[r][q * 4 + 3] = v.w;
            }
        } else {
            constexpr int KF8 = BK / 8;
            for (int i = tid; i < BM * KF8; i += 256) {
                const int r = i / KF8, q = i % KF8;
                const ushort8 v = *(const ushort8*)((const unsigned short*)Am + (size_t)(m0 + r) * lda + k0 + q * 8);
#pragma unroll
                for (int e = 0; e < 8; e++) As[r][q * 8 + e] = bf2f(v[e]);
            }
        }
        {
            constexpr int KF4 = BK / 4;
            for (int i = tid; i < BN * KF4; i += 256) {
                const int r = i / KF4, q = i % KF4;
                const float4 v = *(const float4*)(Wm + (size_t)(n0 + r) * K + k0 + q * 4);
                Ws[r][q * 4 + 0] = v.x; Ws[r][q * 4 + 1] = v.y;
                Ws[r][q * 4 + 2] = v.z; Ws[r][q * 4 + 3] = v.w;
            }
        }
        __syncthreads();
#pragma unroll
        for (int k = 0; k < BK; k++) {
            float ar[TM], wr[TN];
#pragma unroll
            for (int i = 0; i < TM; i++) ar[i] = As[ty * TM + i][k];
#pragma unroll
            for (int j = 0; j < TN; j++) wr[j] = Ws[tx * TN + j][k];
#pragma unroll
            for (int i = 0; i < TM; i++)
#pragma unroll
                for (int j = 0; j < TN; j++)
                    acc[i][j] += ar[i] * wr[j];
        }
        __syncthreads();
    }

#pragma unroll
    for (int i = 0; i < TM; i++) {
        const int row = m0 + ty * TM + i;
        const int col0 = n0 + tx * TN;
#pragma unroll
        for (int j = 0; j < TN; j++) {
            float v = acc[i][j];
            if constexpr (ACT == 2) {
                const float bb = bias[col0 + j];
                v = softplus_f(softplus_f(v + bb) + bb);
            }
            if constexpr (sizeof(TO) == 2)
                ((unsigned short*)C0)[(size_t)row * N + col0 + j] = f2bf(v);
            else
                ((float*)C0)[(size_t)row * N + col0 + j] = v;
        }
    }
}

// conv_state[b][d][k] = u[b, L-4+k, d]  (u bf16 -> f32 out)
__global__ __launch_bounds__(256) void conv_state_kernel(
    const unsigned short* __restrict__ u, float* __restrict__ cs)
{
    const int idx = blockIdx.x * 256 + threadIdx.x;
    if (idx >= B_SZ * D_INNER_ * D_CONV_) return;
    const int k = idx % D_CONV_;
    const int d = (idx / D_CONV_) % D_INNER_;
    const int b = idx / (D_CONV_ * D_INNER_);
    cs[idx] = bf2f(u[((size_t)b * L_SZ + (L_SZ - D_CONV_ + k)) * D_INNER_ + d]);
}

// x = silu(conv_b + depthwise_causal_conv(u)); 8 channels/thread
__global__ __launch_bounds__(256) void conv_silu_kernel(
    const unsigned short* __restrict__ u, const float* __restrict__ cw,
    const float* __restrict__ cb, unsigned short* __restrict__ x)
{
    constexpr int D8 = D_INNER_ / 8;
    const size_t total = (size_t)B_SZ * L_SZ * D8;
    const size_t idx = (size_t)blockIdx.x * 256 + threadIdx.x;
    if (idx >= total) return;
    const int d0 = (int)(idx % D8) * 8;
    const size_t bl = idx / D8;
    const int l = (int)(bl % L_SZ);

    float accv[8];
#pragma unroll
    for (int e = 0; e < 8; e++) accv[e] = cb[d0 + e];

#pragma unroll
    for (int k = 0; k < 4; k++) {
        const int ls = l - 3 + k;
        if (ls >= 0) {
            const ushort8 v = *(const ushort8*)(u + (bl - 3 + k) * D_INNER_ + d0);
#pragma unroll
            for (int e = 0; e < 8; e++)
                accv[e] += bf2f(v[e]) * cw[(d0 + e) * 4 + k];
        }
    }
    ushort8 o;
#pragma unroll
    for (int e = 0; e < 8; e++) o[e] = f2bf(silu_f(accv[e]));
    *(ushort8*)(x + bl * D_INNER_ + d0) = o;
}

// ---------------- chunk-parallel scan ----------------
__global__ __launch_bounds__(256) void scan_pass1(
    const unsigned short* __restrict__ delta, const unsigned short* __restrict__ x,
    const float* __restrict__ xdbl, const float* __restrict__ A_log,
    float* __restrict__ H, float* __restrict__ S)
{
    const int d = blockIdx.x * 256 + threadIdx.x;
    const int c = blockIdx.y;
    const int b = blockIdx.z;

    float a[D_STATE_];
#pragma unroll
    for (int n = 0; n < D_STATE_; n++) a[n] = -expf(A_log[d * D_STATE_ + n]);

    float s[D_STATE_];
#pragma unroll
    for (int n = 0; n < D_STATE_; n++) s[n] = 0.f;
    float sum = 0.f;

    const int t0 = c * CLEN;
    const float* xr = xdbl + ((size_t)b * L_SZ + t0) * 96;
    size_t base = ((size_t)b * L_SZ + t0) * D_INNER_ + d;

    for (int t = 0; t < CLEN; t++) {
        const float dlt = bf2f(delta[base]);
        const float xv  = bf2f(x[base]);
        float4 Bq[4];
#pragma unroll
        for (int q = 0; q < 4; q++) Bq[q] = *(const float4*)(xr + DT_RANK_ + q * 4);
        const float* Bf = (const float*)Bq;
        const float du = dlt * xv;
        sum += dlt;
#pragma unroll
        for (int n = 0; n < D_STATE_; n++)
            s[n] = __expf(dlt * a[n]) * s[n] + du * Bf[n];
        base += D_INNER_;
        xr += 96;
    }

    float* Hp = H + (((size_t)b * NCHUNK + c) * D_INNER_ + d) * D_STATE_;
#pragma unroll
    for (int q = 0; q < 4; q++)
        *(float4*)(Hp + q * 4) = make_float4(s[q*4], s[q*4+1], s[q*4+2], s[q*4+3]);
    S[((size_t)b * NCHUNK + c) * D_INNER_ + d] = sum;
}

__global__ __launch_bounds__(256) void scan_combine(
    const float* __restrict__ A_log, float* __restrict__ H,
    const float* __restrict__ S, float* __restrict__ last_state)
{
    const int idx = blockIdx.x * 256 + threadIdx.x;
    const int d = idx & (D_INNER_ - 1);
    const int b = idx >> 11;

    float a[D_STATE_];
#pragma unroll
    for (int n = 0; n < D_STATE_; n++) a[n] = -expf(A_log[d * D_STATE_ + n]);

    float cur[D_STATE_];
#pragma unroll
    for (int n = 0; n < D_STATE_; n++) cur[n] = 0.f;

    for (int c = 0; c < NCHUNK; c++) {
        float* Hp = H + (((size_t)b * NCHUNK + c) * D_INNER_ + d) * D_STATE_;
        const float Sv = S[((size_t)b * NCHUNK + c) * D_INNER_ + d];
        float h[D_STATE_];
#pragma unroll
        for (int q = 0; q < 4; q++) {
            const float4 v = *(const float4*)(Hp + q * 4);
            h[q*4] = v.x; h[q*4+1] = v.y; h[q*4+2] = v.z; h[q*4+3] = v.w;
        }
        float nxt[D_STATE_];
#pragma unroll
        for (int n = 0; n < D_STATE_; n++)
            nxt[n] = h[n] + __expf(a[n] * Sv) * cur[n];
#pragma unroll
        for (int q = 0; q < 4; q++)
            *(float4*)(Hp + q * 4) = make_float4(cur[q*4], cur[q*4+1], cur[q*4+2], cur[q*4+3]);
#pragma unroll
        for (int n = 0; n < D_STATE_; n++) cur[n] = nxt[n];
    }
#pragma unroll
    for (int n = 0; n < D_STATE_; n++)
        last_state[((size_t)b * D_INNER_ + d) * D_STATE_ + n] = cur[n];
}

__global__ __launch_bounds__(256) void scan_pass3(
    const unsigned short* __restrict__ delta, const unsigned short* __restrict__ x,
    const float* __restrict__ xdbl, const unsigned short* __restrict__ z,
    const float* __restrict__ A_log, const float* __restrict__ Dv,
    const float* __restrict__ H, unsigned short* __restrict__ y)
{
    const int d = blockIdx.x * 256 + threadIdx.x;
    const int c = blockIdx.y;
    const int b = blockIdx.z;

    float a[D_STATE_];
#pragma unroll
    for (int n = 0; n < D_STATE_; n++) a[n] = -expf(A_log[d * D_STATE_ + n]);
    const float Dd = Dv[d];

    const float* Hp = H + (((size_t)b * NCHUNK + c) * D_INNER_ + d) * D_STATE_;
    float s[D_STATE_];
#pragma unroll
    for (int q = 0; q < 4; q++) {
        const float4 v = *(const float4*)(Hp + q * 4);
        s[q*4] = v.x; s[q*4+1] = v.y; s[q*4+2] = v.z; s[q*4+3] = v.w;
    }

    const int t0 = c * CLEN;
    const float* xr = xdbl + ((size_t)b * L_SZ + t0) * 96;
    size_t base = ((size_t)b * L_SZ + t0) * D_INNER_ + d;

    for (int t = 0; t < CLEN; t++) {
        const float dlt = bf2f(delta[base]);
        const float xv  = bf2f(x[base]);
        const float zv  = bf2f(z[base]);
        float4 Bq[4], Cq[4];
#pragma unroll
        for (int q = 0; q < 4; q++) {
            Bq[q] = *(const float4*)(xr + DT_RANK_ + q * 4);
            Cq[q] = *(const float4*)(xr + DT_RANK_ + D_STATE_ + q * 4);
        }
        const float* Bf = (const float*)Bq;
        const float* Cf = (const float*)Cq;
        const float du = dlt * xv;
        float yv = 0.f;
#pragma unroll
        for (int n = 0; n < D_STATE_; n++) {
            s[n] = __expf(dlt * a[n]) * s[n] + du * Bf[n];
            yv += s[n] * Cf[n];
        }
        y[base] = f2bf((yv + xv * Dd) * silu_f(zv));
        base += D_INNER_;
        xr += 96;
    }
}

extern "C" void kernel_launch(void* const* d_in, const int* in_sizes, int n_in,
                              void* d_out, int out_size, void* d_ws, size_t ws_size,
                              hipStream_t stream) {
    const float* hidden     = (const float*)d_in[0];
    const float* in_proj_w  = (const float*)d_in[1];
    const float* conv_w     = (const float*)d_in[2];
    const float* conv_b     = (const float*)d_in[3];
    const float* x_proj_w   = (const float*)d_in[4];
    const float* dt_proj_w  = (const float*)d_in[5];
    const float* dt_proj_b  = (const float*)d_in[6];
    const float* A_log      = (const float*)d_in[7];
    const float* Dvec       = (const float*)d_in[8];
    const float* out_proj_w = (const float*)d_in[9];

    const size_t NT = (size_t)B_SZ * L_SZ * D_INNER_;   // 16,777,216 elems
    // ws layout (79,167,488 B total — identical to proven R4 footprint):
    //   r0   [0,        NT*2)   : u -> delta -> y  (bf16)
    //   xb   [NT*2,     NT*4)   : hb+wib (pre-conv) -> x -> wob  (region reuse)
    //   xdbl [NT*4,     +3.1MB) : x_dbl f32
    //   H    [...,      +8.4MB) : chunk states
    //   S    [...,      +0.5MB) : chunk delta-sums
    const size_t off_xdbl = NT * 4;
    const size_t off_H    = off_xdbl + (size_t)B_SZ * L_SZ * 96 * 4;
    const size_t off_S    = off_H + (size_t)B_SZ * NCHUNK * D_INNER_ * D_STATE_ * 4;
    const size_t required = off_S + (size_t)B_SZ * NCHUNK * D_INNER_ * 4; // 79,167,488
    if (ws_size < required) return;

    char* wsb = (char*)d_ws;
    unsigned short* r0   = (unsigned short*)wsb;
    unsigned short* xb   = (unsigned short*)(wsb + NT * 2);
    float*          xdbl = (float*)(wsb + off_xdbl);
    float*          Hbuf = (float*)(wsb + off_H);
    float*          Sbuf = (float*)(wsb + off_S);

    // bf16 staging areas inside the xb region (dead until conv_silu writes x):
    unsigned short* hb  = xb;                                   // 8192x1024  (16.78 MB)
    unsigned short* wib = xb + (size_t)B_SZ * L_SZ * D_MODEL_;  // 4096x1024  ( 8.39 MB)
    unsigned short* wob = xb;                                   // 1024x2048 after scan

    float* out = (float*)d_out;
    unsigned short* zb = (unsigned short*)d_out;  // z parked in out region
    float* conv_state_out = out + (size_t)B_SZ * L_SZ * D_MODEL_;
    float* last_state_out = conv_state_out + (size_t)B_SZ * D_INNER_ * D_CONV_;

    const int M = B_SZ * L_SZ;  // 8192
    dim3 blk(256);

    // 0) f32 -> bf16 conversions for MFMA operands
    f32_to_bf16_kernel<<<2048, blk, 0, stream>>>(hidden, hb, (int)(M * D_MODEL_ / 4));
    f32_to_bf16_kernel<<<1024, blk, 0, stream>>>(in_proj_w, wib, 2 * D_INNER_ * D_MODEL_ / 4);

    // 1) in_proj (MFMA): [u | z] = hidden @ in_proj_w^T
    gemm_mfma<1><<<dim3((2 * D_INNER_) / 128, M / 128), blk, 0, stream>>>(
        hb, wib, nullptr, r0, zb, M, 2 * D_INNER_, D_MODEL_);

    // 2) conv_state output
    conv_state_kernel<<<(B_SZ * D_INNER_ * D_CONV_ + 255) / 256, blk, 0, stream>>>(
        r0, conv_state_out);

    // 3) depthwise causal conv + SiLU: u -> x (overwrites hb/wib, both dead)
    conv_silu_kernel<<<(B_SZ * L_SZ * (D_INNER_ / 8) + 255) / 256, blk, 0, stream>>>(
        r0, conv_w, conv_b, xb);

    // 4) x_dbl = x @ x_proj_w^T  (skinny, f32 VALU)
    gemm_t<unsigned short, float, 64, 96, 16, 4, 6, 0>
        <<<dim3(1, M / 64), blk, 0, stream>>>(
        xb, D_INNER_, x_proj_w, nullptr, xdbl, M, 96, D_INNER_);

    // 5) delta = softplus(softplus(ts @ dt_proj_w^T + b) + b) -> r0
    gemm_t<float, unsigned short, 128, 128, 16, 8, 8, 2>
        <<<dim3(D_INNER_ / 128, M / 128), blk, 0, stream>>>(
        xdbl, 96, dt_proj_w, dt_proj_b, r0, M, D_INNER_, DT_RANK_);

    // 6) chunk-parallel selective scan (y in place over delta in r0)
    dim3 g13(D_INNER_ / 256, NCHUNK, B_SZ);
    scan_pass1<<<g13, blk, 0, stream>>>(r0, xb, xdbl, A_log, Hbuf, Sbuf);
    scan_combine<<<(B_SZ * D_INNER_) / 256, blk, 0, stream>>>(
        A_log, Hbuf, Sbuf, last_state_out);
    scan_pass3<<<g13, blk, 0, stream>>>(r0, xb, xdbl, zb, A_log, Dvec, Hbuf, r0);

    // 6b) convert out_proj_w (xb region now dead)
    f32_to_bf16_kernel<<<512, blk, 0, stream>>>(out_proj_w, wob, D_MODEL_ * D_INNER_ / 4);

    // 7) out = y @ out_proj_w^T (MFMA, f32 out)
    gemm_mfma<0><<<dim3(D_MODEL_ / 128, M / 128), blk, 0, stream>>>(
        r0, wob, out, nullptr, nullptr, M, D_MODEL_, D_INNER_);
}

// Round 7
// 658.729 us; speedup vs baseline: 7.0344x; 1.4011x over previous
//
#include <hip/hip_runtime.h>
#include <hip/hip_bf16.h>
#include <math.h>

#define B_SZ 2
#define L_SZ 4096
#define D_MODEL_ 1024
#define D_INNER_ 2048
#define D_STATE_ 16
#define D_CONV_ 4
#define DT_RANK_ 64
#define NCHUNK 32
#define CLEN 128   // NCHUNK * CLEN == L_SZ
#define KS_XP 8    // split-K factor for x_proj

typedef unsigned short ushort8 __attribute__((ext_vector_type(8)));
typedef unsigned short ushort4v __attribute__((ext_vector_type(4)));
typedef short mfrag8 __attribute__((ext_vector_type(8)));   // 8 bf16 (4 VGPR) MFMA A/B frag
typedef float facc4 __attribute__((ext_vector_type(4)));    // 4 f32 MFMA C/D frag

__device__ __forceinline__ float bf2f(unsigned short b) {
    return __uint_as_float(((unsigned)b) << 16);
}
__device__ __forceinline__ unsigned short f2bf(float f) {
    unsigned u = __float_as_uint(f);
    unsigned r = (u + 0x7fffu + ((u >> 16) & 1u)) >> 16;  // RNE
    return (unsigned short)r;
}
__device__ __forceinline__ float softplus_f(float x) {
    return (x > 20.f) ? x : log1pf(__expf(x));
}
__device__ __forceinline__ float silu_f(float x) {
    return x / (1.f + __expf(-x));
}
// async global -> LDS, 16B per lane (wave-uniform LDS base, per-lane global src)
__device__ __forceinline__ void gload_lds16(const void* g, void* l) {
    __builtin_amdgcn_global_load_lds(
        (const __attribute__((address_space(1))) unsigned int*)g,
        (__attribute__((address_space(3))) unsigned int*)l,
        16, 0, 0);
}
__device__ __forceinline__ ushort4v cvt4(float4 v) {
    ushort4v o;
    o[0] = f2bf(v.x); o[1] = f2bf(v.y); o[2] = f2bf(v.z); o[3] = f2bf(v.w);
    return o;
}

// ---------------------------------------------------------------------------
// f32 -> bf16 convert (vectorized)
__global__ __launch_bounds__(256) void f32_to_bf16_kernel(
    const float* __restrict__ in, unsigned short* __restrict__ out, int n4)
{
    for (size_t i = (size_t)blockIdx.x * 256 + threadIdx.x; i < (size_t)n4;
         i += (size_t)gridDim.x * 256) {
        *(ushort4v*)(out + i * 4) = cvt4(*(const float4*)(in + i * 4));
    }
}

// ---------------------------------------------------------------------------
// MFMA bf16 GEMM (PROVEN R6): C[M,N] = A[M,K] @ W[N,K]^T
// 128x128 tile, BK=32, 4 waves (2x2), each wave 64x64 via 4x4 16x16x32 frags.
// ACT 0: f32 out to Cf[M,N].  ACT 1: bf16 split at D_INNER_ -> U0 | U1.
template<int ACT>
__global__ __launch_bounds__(256) void gemm_mfma(
    const unsigned short* __restrict__ A,   // [M,K] bf16
    const unsigned short* __restrict__ W,   // [N,K] bf16
    float* __restrict__ Cf,
    unsigned short* __restrict__ U0, unsigned short* __restrict__ U1,
    int M, int N, int K)
{
    constexpr int BK = 32;
    __shared__ __align__(16) char lds[2 * 16384];  // [buf][A 8KB | W 8KB]

    const int tid = threadIdx.x;
    const int l   = tid & 63;
    const int wid = tid >> 6;
    const int wm  = wid >> 1;
    const int wn  = wid & 1;

    const int nwg  = gridDim.x * gridDim.y;
    const int flat = blockIdx.y * gridDim.x + blockIdx.x;
    const int swz  = (flat & 7) * (nwg >> 3) + (flat >> 3);
    const int m0   = (swz / gridDim.x) * 128;
    const int n0   = (swz % gridDim.x) * 128;

    const int rl   = l >> 2;
    const int slot = l & 3;
    const int xsl  = slot ^ ((rl >> 1) & 3);
    const char* a_src[2];
    const char* w_src[2];
#pragma unroll
    for (int i = 0; i < 2; i++) {
        const int r = wid * 32 + i * 16 + rl;
        a_src[i] = (const char*)A + ((size_t)(m0 + r) * K) * 2 + xsl * 16;
        w_src[i] = (const char*)W + ((size_t)(n0 + r) * K) * 2 + xsl * 16;
    }
    const int stg_off = wid * 32 * 64;

    const int srow = l & 15;
    const int kg   = l >> 4;
    const int lo   = srow * 64 + (kg ^ ((srow >> 1) & 3)) * 16;
    int a_off[4], b_off[4];
#pragma unroll
    for (int i = 0; i < 4; i++) {
        a_off[i] = (wm * 64 + i * 16) * 64 + lo;
        b_off[i] = (wn * 64 + i * 16) * 64 + lo;
    }

    const facc4 zf = {0.f, 0.f, 0.f, 0.f};
    facc4 acc[4][4];
#pragma unroll
    for (int i = 0; i < 4; i++)
#pragma unroll
        for (int j = 0; j < 4; j++) acc[i][j] = zf;

    const int KT = K / BK;
#pragma unroll
    for (int i = 0; i < 2; i++) {
        gload_lds16(a_src[i], lds + stg_off + i * 1024);
        gload_lds16(w_src[i], lds + 8192 + stg_off + i * 1024);
    }

    int cur = 0;
    for (int kt = 0; kt < KT; ++kt) {
        __syncthreads();
        if (kt + 1 < KT) {
            const int koff = (kt + 1) * BK * 2;
            char* dstA = lds + (cur ^ 1) * 16384 + stg_off;
#pragma unroll
            for (int i = 0; i < 2; i++) {
                gload_lds16(a_src[i] + koff, dstA + i * 1024);
                gload_lds16(w_src[i] + koff, dstA + 8192 + i * 1024);
            }
        }
        const char* base = lds + cur * 16384;
        mfrag8 af[4], bfr[4];
#pragma unroll
        for (int i = 0; i < 4; i++) af[i]  = *(const mfrag8*)(base + a_off[i]);
#pragma unroll
        for (int i = 0; i < 4; i++) bfr[i] = *(const mfrag8*)(base + 8192 + b_off[i]);
#pragma unroll
        for (int i = 0; i < 4; i++)
#pragma unroll
            for (int j = 0; j < 4; j++)
                acc[i][j] = __builtin_amdgcn_mfma_f32_16x16x32_bf16(af[i], bfr[j], acc[i][j], 0, 0, 0);
        cur ^= 1;
    }

    const int crow = (l >> 4) * 4;
    const int ccol = l & 15;
#pragma unroll
    for (int mi = 0; mi < 4; mi++) {
#pragma unroll
        for (int ni = 0; ni < 4; ni++) {
            const int col = n0 + wn * 64 + ni * 16 + ccol;
            const facc4 v = acc[mi][ni];
#pragma unroll
            for (int rr = 0; rr < 4; rr++) {
                const int row = m0 + wm * 64 + mi * 16 + crow + rr;
                if constexpr (ACT == 0) {
                    Cf[(size_t)row * N + col] = v[rr];
                } else {
                    if (col < D_INNER_)
                        U0[(size_t)row * D_INNER_ + col] = f2bf(v[rr]);
                    else
                        U1[(size_t)row * D_INNER_ + (col - D_INNER_)] = f2bf(v[rr]);
                }
            }
        }
    }
}

// ---------------------------------------------------------------------------
// x_proj split-K MFMA: P[ks][8192][96] partial = x[:,kc:kc+256] @ x_proj_w^T
// BM=128, BN=96, BK=64, 4 waves each own 32 rows (2x6 frags).
// A staged via gload_lds16 (XOR-swz source); W staged f32->bf16 via ds_write.
__global__ __launch_bounds__(256) void gemm_xproj(
    const unsigned short* __restrict__ X,   // [8192][2048] bf16
    const float* __restrict__ Wf,           // [96][2048] f32
    float* __restrict__ P)                  // [KS_XP][8192][96] f32
{
    __shared__ __align__(16) char ldsA[128 * 128];  // 16 KB
    __shared__ __align__(16) char ldsW[96 * 128];   // 12 KB

    const int tid = threadIdx.x;
    const int l   = tid & 63;
    const int wid = tid >> 6;
    const int m0  = blockIdx.x * 128;
    const int kc  = blockIdx.y * (2048 / KS_XP);   // 256-wide K chunk

    const facc4 zf = {0.f, 0.f, 0.f, 0.f};
    facc4 acc[2][6];
#pragma unroll
    for (int i = 0; i < 2; i++)
#pragma unroll
        for (int j = 0; j < 6; j++) acc[i][j] = zf;

    for (int kt = 0; kt < 4; kt++) {
        const int k0 = kc + kt * 64;
        // W f32 loads to regs (before barrier: overlaps prior compute/wait)
        float4 wv[6];
#pragma unroll
        for (int j = 0; j < 6; j++) {
            const int i = tid + 256 * j;           // i < 1536
            const int row = i >> 4, q = i & 15;
            wv[j] = *(const float4*)(Wf + (size_t)row * 2048 + k0 + q * 4);
        }
        __syncthreads();   // (a) all waves done reading LDS from prev iter
        // A: 4 slab loads per wave (8 rows x 128B each); swz on global source
#pragma unroll
        for (int j2 = 0; j2 < 4; j2++) {
            const int row = wid * 32 + j2 * 8 + (l >> 3);
            const int xsl = (l & 7) ^ (row & 7);
            gload_lds16(X + (size_t)(m0 + row) * 2048 + k0 + xsl * 8,
                        ldsA + (wid * 32 + j2 * 8) * 128);
        }
        // W: convert + swizzled ds_write (8B per elem-quad)
#pragma unroll
        for (int j = 0; j < 6; j++) {
            const int i = tid + 256 * j;
            const int row = i >> 4, q = i & 15;
            *(ushort4v*)(ldsW + row * 128 + (((q >> 1) ^ (row & 7)) * 16) + (q & 1) * 8) = cvt4(wv[j]);
        }
        __syncthreads();   // (b) staging drained (vmcnt+lgkmcnt before barrier)
#pragma unroll
        for (int ks = 0; ks < 2; ks++) {
            mfrag8 af[2], bf6[6];
#pragma unroll
            for (int mi = 0; mi < 2; mi++) {
                const int row = wid * 32 + mi * 16 + (l & 15);
                af[mi] = *(const mfrag8*)(ldsA + row * 128 + (((ks * 4 + (l >> 4)) ^ (row & 7)) * 16));
            }
#pragma unroll
            for (int ni = 0; ni < 6; ni++) {
                const int row = ni * 16 + (l & 15);
                bf6[ni] = *(const mfrag8*)(ldsW + row * 128 + (((ks * 4 + (l >> 4)) ^ (row & 7)) * 16));
            }
#pragma unroll
            for (int mi = 0; mi < 2; mi++)
#pragma unroll
                for (int ni = 0; ni < 6; ni++)
                    acc[mi][ni] = __builtin_amdgcn_mfma_f32_16x16x32_bf16(af[mi], bf6[ni], acc[mi][ni], 0, 0, 0);
        }
    }

    const int crow = (l >> 4) * 4;
    const int ccol = l & 15;
    float* Pb = P + (size_t)blockIdx.y * (8192 * 96);
#pragma unroll
    for (int mi = 0; mi < 2; mi++) {
#pragma unroll
        for (int ni = 0; ni < 6; ni++) {
            const int col = ni * 16 + ccol;
            const facc4 v = acc[mi][ni];
#pragma unroll
            for (int rr = 0; rr < 4; rr++) {
                const int row = m0 + wid * 32 + mi * 16 + crow + rr;
                Pb[(size_t)row * 96 + col] = v[rr];
            }
        }
    }
}

// reduce split-K partials: xdbl = sum_ks P[ks]
__global__ __launch_bounds__(256) void reduce_xproj(
    const float* __restrict__ P, float* __restrict__ xdbl)
{
    const int i = blockIdx.x * 256 + threadIdx.x;   // float4 index < 196608
    const float4* p = (const float4*)P;
    float4 s = p[i];
#pragma unroll
    for (int k = 1; k < KS_XP; k++) {
        const float4 v = p[i + k * 196608];
        s.x += v.x; s.y += v.y; s.z += v.z; s.w += v.w;
    }
    ((float4*)xdbl)[i] = s;
}

// ---------------------------------------------------------------------------
// dt_proj one-shot MFMA (K=64): delta = sp(sp(ts @ dt_w^T + b) + b), bf16 out.
// Stages both operands f32->bf16 via swizzled ds_write; 128x128 tile, 4 waves.
__global__ __launch_bounds__(256) void gemm_dt(
    const float* __restrict__ xd,    // [8192][96] f32, cols 0..64 = ts
    const float* __restrict__ Wf,    // [2048][64] f32
    const float* __restrict__ bias,  // [2048]
    unsigned short* __restrict__ delta)  // [8192][2048] bf16
{
    __shared__ __align__(16) char ldsA[128 * 128];
    __shared__ __align__(16) char ldsW[128 * 128];

    const int tid = threadIdx.x;
    const int l   = tid & 63;
    const int wid = tid >> 6;
    const int wm  = wid >> 1;
    const int wn  = wid & 1;
    const int m0  = blockIdx.y * 128;
    const int n0  = blockIdx.x * 128;

#pragma unroll
    for (int j = 0; j < 8; j++) {
        const int i = tid + 256 * j;               // i < 2048
        const int row = i >> 4, q = i & 15;
        const float4 av = *(const float4*)(xd + (size_t)(m0 + row) * 96 + q * 4);
        const float4 wv = *(const float4*)(Wf + (size_t)(n0 + row) * 64 + q * 4);
        const int off = row * 128 + (((q >> 1) ^ (row & 7)) * 16) + (q & 1) * 8;
        *(ushort4v*)(ldsA + off) = cvt4(av);
        *(ushort4v*)(ldsW + off) = cvt4(wv);
    }
    __syncthreads();

    const facc4 zf = {0.f, 0.f, 0.f, 0.f};
    facc4 acc[4][4];
#pragma unroll
    for (int i = 0; i < 4; i++)
#pragma unroll
        for (int j = 0; j < 4; j++) acc[i][j] = zf;

#pragma unroll
    for (int ks = 0; ks < 2; ks++) {
        mfrag8 af[4], bfr[4];
#pragma unroll
        for (int mi = 0; mi < 4; mi++) {
            const int row = wm * 64 + mi * 16 + (l & 15);
            af[mi] = *(const mfrag8*)(ldsA + row * 128 + (((ks * 4 + (l >> 4)) ^ (row & 7)) * 16));
        }
#pragma unroll
        for (int ni = 0; ni < 4; ni++) {
            const int row = wn * 64 + ni * 16 + (l & 15);
            bfr[ni] = *(const mfrag8*)(ldsW + row * 128 + (((ks * 4 + (l >> 4)) ^ (row & 7)) * 16));
        }
#pragma unroll
        for (int mi = 0; mi < 4; mi++)
#pragma unroll
            for (int ni = 0; ni < 4; ni++)
                acc[mi][ni] = __builtin_amdgcn_mfma_f32_16x16x32_bf16(af[mi], bfr[ni], acc[mi][ni], 0, 0, 0);
    }

    const int crow = (l >> 4) * 4;
    const int ccol = l & 15;
#pragma unroll
    for (int mi = 0; mi < 4; mi++) {
#pragma unroll
        for (int ni = 0; ni < 4; ni++) {
            const int col = n0 + wn * 64 + ni * 16 + ccol;
            const float bb = bias[col];
            const facc4 v = acc[mi][ni];
#pragma unroll
            for (int rr = 0; rr < 4; rr++) {
                const int row = m0 + wm * 64 + mi * 16 + crow + rr;
                delta[(size_t)row * D_INNER_ + col] = f2bf(softplus_f(softplus_f(v[rr] + bb) + bb));
            }
        }
    }
}

// conv_state[b][d][k] = u[b, L-4+k, d]  (u bf16 -> f32 out)
__global__ __launch_bounds__(256) void conv_state_kernel(
    const unsigned short* __restrict__ u, float* __restrict__ cs)
{
    const int idx = blockIdx.x * 256 + threadIdx.x;
    if (idx >= B_SZ * D_INNER_ * D_CONV_) return;
    const int k = idx % D_CONV_;
    const int d = (idx / D_CONV_) % D_INNER_;
    const int b = idx / (D_CONV_ * D_INNER_);
    cs[idx] = bf2f(u[((size_t)b * L_SZ + (L_SZ - D_CONV_ + k)) * D_INNER_ + d]);
}

// x = silu(conv_b + depthwise_causal_conv(u)); 8 channels/thread
__global__ __launch_bounds__(256) void conv_silu_kernel(
    const unsigned short* __restrict__ u, const float* __restrict__ cw,
    const float* __restrict__ cb, unsigned short* __restrict__ x)
{
    constexpr int D8 = D_INNER_ / 8;
    const size_t total = (size_t)B_SZ * L_SZ * D8;
    const size_t idx = (size_t)blockIdx.x * 256 + threadIdx.x;
    if (idx >= total) return;
    const int d0 = (int)(idx % D8) * 8;
    const size_t bl = idx / D8;
    const int l = (int)(bl % L_SZ);

    float accv[8];
#pragma unroll
    for (int e = 0; e < 8; e++) accv[e] = cb[d0 + e];

#pragma unroll
    for (int k = 0; k < 4; k++) {
        const int ls = l - 3 + k;
        if (ls >= 0) {
            const ushort8 v = *(const ushort8*)(u + (bl - 3 + k) * D_INNER_ + d0);
#pragma unroll
            for (int e = 0; e < 8; e++)
                accv[e] += bf2f(v[e]) * cw[(d0 + e) * 4 + k];
        }
    }
    ushort8 o;
#pragma unroll
    for (int e = 0; e < 8; e++) o[e] = f2bf(silu_f(accv[e]));
    *(ushort8*)(x + bl * D_INNER_ + d0) = o;
}

// ---------------- chunk-parallel scan (proven R4) ----------------
__global__ __launch_bounds__(256) void scan_pass1(
    const unsigned short* __restrict__ delta, const unsigned short* __restrict__ x,
    const float* __restrict__ xdbl, const float* __restrict__ A_log,
    float* __restrict__ H, float* __restrict__ S)
{
    const int d = blockIdx.x * 256 + threadIdx.x;
    const int c = blockIdx.y;
    const int b = blockIdx.z;

    float a[D_STATE_];
#pragma unroll
    for (int n = 0; n < D_STATE_; n++) a[n] = -expf(A_log[d * D_STATE_ + n]);

    float s[D_STATE_];
#pragma unroll
    for (int n = 0; n < D_STATE_; n++) s[n] = 0.f;
    float sum = 0.f;

    const int t0 = c * CLEN;
    const float* xr = xdbl + ((size_t)b * L_SZ + t0) * 96;
    size_t base = ((size_t)b * L_SZ + t0) * D_INNER_ + d;

    for (int t = 0; t < CLEN; t++) {
        const float dlt = bf2f(delta[base]);
        const float xv  = bf2f(x[base]);
        float4 Bq[4];
#pragma unroll
        for (int q = 0; q < 4; q++) Bq[q] = *(const float4*)(xr + DT_RANK_ + q * 4);
        const float* Bf = (const float*)Bq;
        const float du = dlt * xv;
        sum += dlt;
#pragma unroll
        for (int n = 0; n < D_STATE_; n++)
            s[n] = __expf(dlt * a[n]) * s[n] + du * Bf[n];
        base += D_INNER_;
        xr += 96;
    }

    float* Hp = H + (((size_t)b * NCHUNK + c) * D_INNER_ + d) * D_STATE_;
#pragma unroll
    for (int q = 0; q < 4; q++)
        *(float4*)(Hp + q * 4) = make_float4(s[q*4], s[q*4+1], s[q*4+2], s[q*4+3]);
    S[((size_t)b * NCHUNK + c) * D_INNER_ + d] = sum;
}

__global__ __launch_bounds__(256) void scan_combine(
    const float* __restrict__ A_log, float* __restrict__ H,
    const float* __restrict__ S, float* __restrict__ last_state)
{
    const int idx = blockIdx.x * 256 + threadIdx.x;
    const int d = idx & (D_INNER_ - 1);
    const int b = idx >> 11;

    float a[D_STATE_];
#pragma unroll
    for (int n = 0; n < D_STATE_; n++) a[n] = -expf(A_log[d * D_STATE_ + n]);

    float cur[D_STATE_];
#pragma unroll
    for (int n = 0; n < D_STATE_; n++) cur[n] = 0.f;

    for (int c = 0; c < NCHUNK; c++) {
        float* Hp = H + (((size_t)b * NCHUNK + c) * D_INNER_ + d) * D_STATE_;
        const float Sv = S[((size_t)b * NCHUNK + c) * D_INNER_ + d];
        float h[D_STATE_];
#pragma unroll
        for (int q = 0; q < 4; q++) {
            const float4 v = *(const float4*)(Hp + q * 4);
            h[q*4] = v.x; h[q*4+1] = v.y; h[q*4+2] = v.z; h[q*4+3] = v.w;
        }
        float nxt[D_STATE_];
#pragma unroll
        for (int n = 0; n < D_STATE_; n++)
            nxt[n] = h[n] + __expf(a[n] * Sv) * cur[n];
#pragma unroll
        for (int q = 0; q < 4; q++)
            *(float4*)(Hp + q * 4) = make_float4(cur[q*4], cur[q*4+1], cur[q*4+2], cur[q*4+3]);
#pragma unroll
        for (int n = 0; n < D_STATE_; n++) cur[n] = nxt[n];
    }
#pragma unroll
    for (int n = 0; n < D_STATE_; n++)
        last_state[((size_t)b * D_INNER_ + d) * D_STATE_ + n] = cur[n];
}

__global__ __launch_bounds__(256) void scan_pass3(
    const unsigned short* __restrict__ delta, const unsigned short* __restrict__ x,
    const float* __restrict__ xdbl, const unsigned short* __restrict__ z,
    const float* __restrict__ A_log, const float* __restrict__ Dv,
    const float* __restrict__ H, unsigned short* __restrict__ y)
{
    const int d = blockIdx.x * 256 + threadIdx.x;
    const int c = blockIdx.y;
    const int b = blockIdx.z;

    float a[D_STATE_];
#pragma unroll
    for (int n = 0; n < D_STATE_; n++) a[n] = -expf(A_log[d * D_STATE_ + n]);
    const float Dd = Dv[d];

    const float* Hp = H + (((size_t)b * NCHUNK + c) * D_INNER_ + d) * D_STATE_;
    float s[D_STATE_];
#pragma unroll
    for (int q = 0; q < 4; q++) {
        const float4 v = *(const float4*)(Hp + q * 4);
        s[q*4] = v.x; s[q*4+1] = v.y; s[q*4+2] = v.z; s[q*4+3] = v.w;
    }

    const int t0 = c * CLEN;
    const float* xr = xdbl + ((size_t)b * L_SZ + t0) * 96;
    size_t base = ((size_t)b * L_SZ + t0) * D_INNER_ + d;

    for (int t = 0; t < CLEN; t++) {
        const float dlt = bf2f(delta[base]);
        const float xv  = bf2f(x[base]);
        const float zv  = bf2f(z[base]);
        float4 Bq[4], Cq[4];
#pragma unroll
        for (int q = 0; q < 4; q++) {
            Bq[q] = *(const float4*)(xr + DT_RANK_ + q * 4);
            Cq[q] = *(const float4*)(xr + DT_RANK_ + D_STATE_ + q * 4);
        }
        const float* Bf = (const float*)Bq;
        const float* Cf = (const float*)Cq;
        const float du = dlt * xv;
        float yv = 0.f;
#pragma unroll
        for (int n = 0; n < D_STATE_; n++) {
            s[n] = __expf(dlt * a[n]) * s[n] + du * Bf[n];
            yv += s[n] * Cf[n];
        }
        y[base] = f2bf((yv + xv * Dd) * silu_f(zv));
        base += D_INNER_;
        xr += 96;
    }
}

extern "C" void kernel_launch(void* const* d_in, const int* in_sizes, int n_in,
                              void* d_out, int out_size, void* d_ws, size_t ws_size,
                              hipStream_t stream) {
    const float* hidden     = (const float*)d_in[0];
    const float* in_proj_w  = (const float*)d_in[1];
    const float* conv_w     = (const float*)d_in[2];
    const float* conv_b     = (const float*)d_in[3];
    const float* x_proj_w   = (const float*)d_in[4];
    const float* dt_proj_w  = (const float*)d_in[5];
    const float* dt_proj_b  = (const float*)d_in[6];
    const float* A_log      = (const float*)d_in[7];
    const float* Dvec       = (const float*)d_in[8];
    const float* out_proj_w = (const float*)d_in[9];

    const size_t NT = (size_t)B_SZ * L_SZ * D_INNER_;   // 16,777,216 elems
    // ws layout (79,167,488 B total — identical to proven R4/R6 footprint):
    //   r0   [0,     NT*2)   : u -> xproj partials P (25.2MB<32MB) -> delta -> y
    //   xb   [NT*2,  NT*4)   : hb+wib (pre-conv) -> x -> wob
    //   xdbl [NT*4,  +3.1MB) : x_dbl f32
    //   H / S                : chunk states / delta-sums
    const size_t off_xdbl = NT * 4;
    const size_t off_H    = off_xdbl + (size_t)B_SZ * L_SZ * 96 * 4;
    const size_t off_S    = off_H + (size_t)B_SZ * NCHUNK * D_INNER_ * D_STATE_ * 4;
    const size_t required = off_S + (size_t)B_SZ * NCHUNK * D_INNER_ * 4; // 79,167,488
    if (ws_size < required) return;

    char* wsb = (char*)d_ws;
    unsigned short* r0   = (unsigned short*)wsb;
    unsigned short* xb   = (unsigned short*)(wsb + NT * 2);
    float*          xdbl = (float*)(wsb + off_xdbl);
    float*          Hbuf = (float*)(wsb + off_H);
    float*          Sbuf = (float*)(wsb + off_S);
    float*          Pbuf = (float*)wsb;   // x_proj partials, in dead r0 window

    unsigned short* hb  = xb;                                   // 8192x1024
    unsigned short* wib = xb + (size_t)B_SZ * L_SZ * D_MODEL_;  // 4096x1024
    unsigned short* wob = xb;                                   // 1024x2048 after scan

    float* out = (float*)d_out;
    unsigned short* zb = (unsigned short*)d_out;  // z parked in out region
    float* conv_state_out = out + (size_t)B_SZ * L_SZ * D_MODEL_;
    float* last_state_out = conv_state_out + (size_t)B_SZ * D_INNER_ * D_CONV_;

    const int M = B_SZ * L_SZ;  // 8192
    dim3 blk(256);

    // 0) f32 -> bf16 conversions for MFMA operands
    f32_to_bf16_kernel<<<2048, blk, 0, stream>>>(hidden, hb, (int)(M * D_MODEL_ / 4));
    f32_to_bf16_kernel<<<1024, blk, 0, stream>>>(in_proj_w, wib, 2 * D_INNER_ * D_MODEL_ / 4);

    // 1) in_proj (MFMA): [u | z] = hidden @ in_proj_w^T
    gemm_mfma<1><<<dim3((2 * D_INNER_) / 128, M / 128), blk, 0, stream>>>(
        hb, wib, nullptr, r0, zb, M, 2 * D_INNER_, D_MODEL_);

    // 2) conv_state output
    conv_state_kernel<<<(B_SZ * D_INNER_ * D_CONV_ + 255) / 256, blk, 0, stream>>>(
        r0, conv_state_out);

    // 3) depthwise causal conv + SiLU: u -> x
    conv_silu_kernel<<<(B_SZ * L_SZ * (D_INNER_ / 8) + 255) / 256, blk, 0, stream>>>(
        r0, conv_w, conv_b, xb);

    // 4) x_dbl = x @ x_proj_w^T (split-K MFMA into r0-resident partials, then reduce)
    gemm_xproj<<<dim3(M / 128, KS_XP), blk, 0, stream>>>(xb, x_proj_w, Pbuf);
    reduce_xproj<<<(M * 96 / 4) / 256, blk, 0, stream>>>(Pbuf, xdbl);

    // 5) delta = sp(sp(ts @ dt_w^T + b) + b) -> r0 (one-shot MFMA, overwrites P)
    gemm_dt<<<dim3(D_INNER_ / 128, M / 128), blk, 0, stream>>>(
        xdbl, dt_proj_w, dt_proj_b, r0);

    // 6) chunk-parallel selective scan (y in place over delta in r0)
    dim3 g13(D_INNER_ / 256, NCHUNK, B_SZ);
    scan_pass1<<<g13, blk, 0, stream>>>(r0, xb, xdbl, A_log, Hbuf, Sbuf);
    scan_combine<<<(B_SZ * D_INNER_) / 256, blk, 0, stream>>>(
        A_log, Hbuf, Sbuf, last_state_out);
    scan_pass3<<<g13, blk, 0, stream>>>(r0, xb, xdbl, zb, A_log, Dvec, Hbuf, r0);

    // 6b) convert out_proj_w (xb region now dead)
    f32_to_bf16_kernel<<<512, blk, 0, stream>>>(out_proj_w, wob, D_MODEL_ * D_INNER_ / 4);

    // 7) out = y @ out_proj_w^T (MFMA, f32 out)
    gemm_mfma<0><<<dim3(D_MODEL_ / 128, M / 128), blk, 0, stream>>>(
        r0, wob, out, nullptr, nullptr, M, D_MODEL_, D_INNER_);
}

// Round 8
// 561.896 us; speedup vs baseline: 8.2467x; 1.1723x over previous
//
#include <hip/hip_runtime.h>
#include <hip/hip_bf16.h>
#include <math.h>

#define B_SZ 2
#define L_SZ 4096
#define D_MODEL_ 1024
#define D_INNER_ 2048
#define D_STATE_ 16
#define D_CONV_ 4
#define DT_RANK_ 64
#define NCHUNK 32
#define CLEN 128   // NCHUNK * CLEN == L_SZ
#define KS_XP 8    // split-K factor for x_proj

typedef unsigned short ushort8 __attribute__((ext_vector_type(8)));
typedef unsigned short ushort4v __attribute__((ext_vector_type(4)));
typedef short mfrag8 __attribute__((ext_vector_type(8)));   // 8 bf16 (4 VGPR) MFMA A/B frag
typedef float facc4 __attribute__((ext_vector_type(4)));    // 4 f32 MFMA C/D frag

__device__ __forceinline__ float bf2f(unsigned short b) {
    return __uint_as_float(((unsigned)b) << 16);
}
__device__ __forceinline__ unsigned short f2bf(float f) {
    unsigned u = __float_as_uint(f);
    unsigned r = (u + 0x7fffu + ((u >> 16) & 1u)) >> 16;  // RNE
    return (unsigned short)r;
}
__device__ __forceinline__ float softplus_f(float x) {
    return (x > 20.f) ? x : log1pf(__expf(x));
}
__device__ __forceinline__ float silu_f(float x) {
    return x / (1.f + __expf(-x));
}
// async global -> LDS, 16B per lane (wave-uniform LDS base, per-lane global src)
__device__ __forceinline__ void gload_lds16(const void* g, void* l) {
    __builtin_amdgcn_global_load_lds(
        (const __attribute__((address_space(1))) unsigned int*)g,
        (__attribute__((address_space(3))) unsigned int*)l,
        16, 0, 0);
}
__device__ __forceinline__ ushort4v cvt4(float4 v) {
    ushort4v o;
    o[0] = f2bf(v.x); o[1] = f2bf(v.y); o[2] = f2bf(v.z); o[3] = f2bf(v.w);
    return o;
}

// ---------------------------------------------------------------------------
// f32 -> bf16 convert (vectorized)
__global__ __launch_bounds__(256) void f32_to_bf16_kernel(
    const float* __restrict__ in, unsigned short* __restrict__ out, int n4)
{
    for (size_t i = (size_t)blockIdx.x * 256 + threadIdx.x; i < (size_t)n4;
         i += (size_t)gridDim.x * 256) {
        *(ushort4v*)(out + i * 4) = cvt4(*(const float4*)(in + i * 4));
    }
}

// ---------------------------------------------------------------------------
// MFMA bf16 GEMM (PROVEN R6): C[M,N] = A[M,K] @ W[N,K]^T
// 128x128 tile, BK=32, 4 waves (2x2), each wave 64x64 via 4x4 16x16x32 frags.
// ACT 0: f32 out to Cf[M,N].  ACT 1: bf16 split at D_INNER_ -> U0 | U1.
template<int ACT>
__global__ __launch_bounds__(256) void gemm_mfma(
    const unsigned short* __restrict__ A,   // [M,K] bf16
    const unsigned short* __restrict__ W,   // [N,K] bf16
    float* __restrict__ Cf,
    unsigned short* __restrict__ U0, unsigned short* __restrict__ U1,
    int M, int N, int K)
{
    constexpr int BK = 32;
    __shared__ __align__(16) char lds[2 * 16384];  // [buf][A 8KB | W 8KB]

    const int tid = threadIdx.x;
    const int l   = tid & 63;
    const int wid = tid >> 6;
    const int wm  = wid >> 1;
    const int wn  = wid & 1;

    const int nwg  = gridDim.x * gridDim.y;
    const int flat = blockIdx.y * gridDim.x + blockIdx.x;
    const int swz  = (flat & 7) * (nwg >> 3) + (flat >> 3);
    const int m0   = (swz / gridDim.x) * 128;
    const int n0   = (swz % gridDim.x) * 128;

    const int rl   = l >> 2;
    const int slot = l & 3;
    const int xsl  = slot ^ ((rl >> 1) & 3);
    const char* a_src[2];
    const char* w_src[2];
#pragma unroll
    for (int i = 0; i < 2; i++) {
        const int r = wid * 32 + i * 16 + rl;
        a_src[i] = (const char*)A + ((size_t)(m0 + r) * K) * 2 + xsl * 16;
        w_src[i] = (const char*)W + ((size_t)(n0 + r) * K) * 2 + xsl * 16;
    }
    const int stg_off = wid * 32 * 64;

    const int srow = l & 15;
    const int kg   = l >> 4;
    const int lo   = srow * 64 + (kg ^ ((srow >> 1) & 3)) * 16;
    int a_off[4], b_off[4];
#pragma unroll
    for (int i = 0; i < 4; i++) {
        a_off[i] = (wm * 64 + i * 16) * 64 + lo;
        b_off[i] = (wn * 64 + i * 16) * 64 + lo;
    }

    const facc4 zf = {0.f, 0.f, 0.f, 0.f};
    facc4 acc[4][4];
#pragma unroll
    for (int i = 0; i < 4; i++)
#pragma unroll
        for (int j = 0; j < 4; j++) acc[i][j] = zf;

    const int KT = K / BK;
#pragma unroll
    for (int i = 0; i < 2; i++) {
        gload_lds16(a_src[i], lds + stg_off + i * 1024);
        gload_lds16(w_src[i], lds + 8192 + stg_off + i * 1024);
    }

    int cur = 0;
    for (int kt = 0; kt < KT; ++kt) {
        __syncthreads();
        if (kt + 1 < KT) {
            const int koff = (kt + 1) * BK * 2;
            char* dstA = lds + (cur ^ 1) * 16384 + stg_off;
#pragma unroll
            for (int i = 0; i < 2; i++) {
                gload_lds16(a_src[i] + koff, dstA + i * 1024);
                gload_lds16(w_src[i] + koff, dstA + 8192 + i * 1024);
            }
        }
        const char* base = lds + cur * 16384;
        mfrag8 af[4], bfr[4];
#pragma unroll
        for (int i = 0; i < 4; i++) af[i]  = *(const mfrag8*)(base + a_off[i]);
#pragma unroll
        for (int i = 0; i < 4; i++) bfr[i] = *(const mfrag8*)(base + 8192 + b_off[i]);
#pragma unroll
        for (int i = 0; i < 4; i++)
#pragma unroll
            for (int j = 0; j < 4; j++)
                acc[i][j] = __builtin_amdgcn_mfma_f32_16x16x32_bf16(af[i], bfr[j], acc[i][j], 0, 0, 0);
        cur ^= 1;
    }

    const int crow = (l >> 4) * 4;
    const int ccol = l & 15;
#pragma unroll
    for (int mi = 0; mi < 4; mi++) {
#pragma unroll
        for (int ni = 0; ni < 4; ni++) {
            const int col = n0 + wn * 64 + ni * 16 + ccol;
            const facc4 v = acc[mi][ni];
#pragma unroll
            for (int rr = 0; rr < 4; rr++) {
                const int row = m0 + wm * 64 + mi * 16 + crow + rr;
                if constexpr (ACT == 0) {
                    Cf[(size_t)row * N + col] = v[rr];
                } else {
                    if (col < D_INNER_)
                        U0[(size_t)row * D_INNER_ + col] = f2bf(v[rr]);
                    else
                        U1[(size_t)row * D_INNER_ + (col - D_INNER_)] = f2bf(v[rr]);
                }
            }
        }
    }
}

// ---------------------------------------------------------------------------
// x_proj split-K MFMA (proven R7)
__global__ __launch_bounds__(256) void gemm_xproj(
    const unsigned short* __restrict__ X,   // [8192][2048] bf16
    const float* __restrict__ Wf,           // [96][2048] f32
    float* __restrict__ P)                  // [KS_XP][8192][96] f32
{
    __shared__ __align__(16) char ldsA[128 * 128];  // 16 KB
    __shared__ __align__(16) char ldsW[96 * 128];   // 12 KB

    const int tid = threadIdx.x;
    const int l   = tid & 63;
    const int wid = tid >> 6;
    const int m0  = blockIdx.x * 128;
    const int kc  = blockIdx.y * (2048 / KS_XP);   // 256-wide K chunk

    const facc4 zf = {0.f, 0.f, 0.f, 0.f};
    facc4 acc[2][6];
#pragma unroll
    for (int i = 0; i < 2; i++)
#pragma unroll
        for (int j = 0; j < 6; j++) acc[i][j] = zf;

    for (int kt = 0; kt < 4; kt++) {
        const int k0 = kc + kt * 64;
        float4 wv[6];
#pragma unroll
        for (int j = 0; j < 6; j++) {
            const int i = tid + 256 * j;           // i < 1536
            const int row = i >> 4, q = i & 15;
            wv[j] = *(const float4*)(Wf + (size_t)row * 2048 + k0 + q * 4);
        }
        __syncthreads();
#pragma unroll
        for (int j2 = 0; j2 < 4; j2++) {
            const int row = wid * 32 + j2 * 8 + (l >> 3);
            const int xsl = (l & 7) ^ (row & 7);
            gload_lds16(X + (size_t)(m0 + row) * 2048 + k0 + xsl * 8,
                        ldsA + (wid * 32 + j2 * 8) * 128);
        }
#pragma unroll
        for (int j = 0; j < 6; j++) {
            const int i = tid + 256 * j;
            const int row = i >> 4, q = i & 15;
            *(ushort4v*)(ldsW + row * 128 + (((q >> 1) ^ (row & 7)) * 16) + (q & 1) * 8) = cvt4(wv[j]);
        }
        __syncthreads();
#pragma unroll
        for (int ks = 0; ks < 2; ks++) {
            mfrag8 af[2], bf6[6];
#pragma unroll
            for (int mi = 0; mi < 2; mi++) {
                const int row = wid * 32 + mi * 16 + (l & 15);
                af[mi] = *(const mfrag8*)(ldsA + row * 128 + (((ks * 4 + (l >> 4)) ^ (row & 7)) * 16));
            }
#pragma unroll
            for (int ni = 0; ni < 6; ni++) {
                const int row = ni * 16 + (l & 15);
                bf6[ni] = *(const mfrag8*)(ldsW + row * 128 + (((ks * 4 + (l >> 4)) ^ (row & 7)) * 16));
            }
#pragma unroll
            for (int mi = 0; mi < 2; mi++)
#pragma unroll
                for (int ni = 0; ni < 6; ni++)
                    acc[mi][ni] = __builtin_amdgcn_mfma_f32_16x16x32_bf16(af[mi], bf6[ni], acc[mi][ni], 0, 0, 0);
        }
    }

    const int crow = (l >> 4) * 4;
    const int ccol = l & 15;
    float* Pb = P + (size_t)blockIdx.y * (8192 * 96);
#pragma unroll
    for (int mi = 0; mi < 2; mi++) {
#pragma unroll
        for (int ni = 0; ni < 6; ni++) {
            const int col = ni * 16 + ccol;
            const facc4 v = acc[mi][ni];
#pragma unroll
            for (int rr = 0; rr < 4; rr++) {
                const int row = m0 + wid * 32 + mi * 16 + crow + rr;
                Pb[(size_t)row * 96 + col] = v[rr];
            }
        }
    }
}

// reduce split-K partials: xdbl = sum_ks P[ks]
__global__ __launch_bounds__(256) void reduce_xproj(
    const float* __restrict__ P, float* __restrict__ xdbl)
{
    const int i = blockIdx.x * 256 + threadIdx.x;   // float4 index < 196608
    const float4* p = (const float4*)P;
    float4 s = p[i];
#pragma unroll
    for (int k = 1; k < KS_XP; k++) {
        const float4 v = p[i + k * 196608];
        s.x += v.x; s.y += v.y; s.z += v.z; s.w += v.w;
    }
    ((float4*)xdbl)[i] = s;
}

// ---------------------------------------------------------------------------
// dt_proj one-shot MFMA (proven R7)
__global__ __launch_bounds__(256) void gemm_dt(
    const float* __restrict__ xd,    // [8192][96] f32, cols 0..64 = ts
    const float* __restrict__ Wf,    // [2048][64] f32
    const float* __restrict__ bias,  // [2048]
    unsigned short* __restrict__ delta)  // [8192][2048] bf16
{
    __shared__ __align__(16) char ldsA[128 * 128];
    __shared__ __align__(16) char ldsW[128 * 128];

    const int tid = threadIdx.x;
    const int l   = tid & 63;
    const int wid = tid >> 6;
    const int wm  = wid >> 1;
    const int wn  = wid & 1;
    const int m0  = blockIdx.y * 128;
    const int n0  = blockIdx.x * 128;

#pragma unroll
    for (int j = 0; j < 8; j++) {
        const int i = tid + 256 * j;               // i < 2048
        const int row = i >> 4, q = i & 15;
        const float4 av = *(const float4*)(xd + (size_t)(m0 + row) * 96 + q * 4);
        const float4 wv = *(const float4*)(Wf + (size_t)(n0 + row) * 64 + q * 4);
        const int off = row * 128 + (((q >> 1) ^ (row & 7)) * 16) + (q & 1) * 8;
        *(ushort4v*)(ldsA + off) = cvt4(av);
        *(ushort4v*)(ldsW + off) = cvt4(wv);
    }
    __syncthreads();

    const facc4 zf = {0.f, 0.f, 0.f, 0.f};
    facc4 acc[4][4];
#pragma unroll
    for (int i = 0; i < 4; i++)
#pragma unroll
        for (int j = 0; j < 4; j++) acc[i][j] = zf;

#pragma unroll
    for (int ks = 0; ks < 2; ks++) {
        mfrag8 af[4], bfr[4];
#pragma unroll
        for (int mi = 0; mi < 4; mi++) {
            const int row = wm * 64 + mi * 16 + (l & 15);
            af[mi] = *(const mfrag8*)(ldsA + row * 128 + (((ks * 4 + (l >> 4)) ^ (row & 7)) * 16));
        }
#pragma unroll
        for (int ni = 0; ni < 4; ni++) {
            const int row = wn * 64 + ni * 16 + (l & 15);
            bfr[ni] = *(const mfrag8*)(ldsW + row * 128 + (((ks * 4 + (l >> 4)) ^ (row & 7)) * 16));
        }
#pragma unroll
        for (int mi = 0; mi < 4; mi++)
#pragma unroll
            for (int ni = 0; ni < 4; ni++)
                acc[mi][ni] = __builtin_amdgcn_mfma_f32_16x16x32_bf16(af[mi], bfr[ni], acc[mi][ni], 0, 0, 0);
    }

    const int crow = (l >> 4) * 4;
    const int ccol = l & 15;
#pragma unroll
    for (int mi = 0; mi < 4; mi++) {
#pragma unroll
        for (int ni = 0; ni < 4; ni++) {
            const int col = n0 + wn * 64 + ni * 16 + ccol;
            const float bb = bias[col];
            const facc4 v = acc[mi][ni];
#pragma unroll
            for (int rr = 0; rr < 4; rr++) {
                const int row = m0 + wm * 64 + mi * 16 + crow + rr;
                delta[(size_t)row * D_INNER_ + col] = f2bf(softplus_f(softplus_f(v[rr] + bb) + bb));
            }
        }
    }
}

// conv_state[b][d][k] = u[b, L-4+k, d]  (u bf16 -> f32 out)
__global__ __launch_bounds__(256) void conv_state_kernel(
    const unsigned short* __restrict__ u, float* __restrict__ cs)
{
    const int idx = blockIdx.x * 256 + threadIdx.x;
    if (idx >= B_SZ * D_INNER_ * D_CONV_) return;
    const int k = idx % D_CONV_;
    const int d = (idx / D_CONV_) % D_INNER_;
    const int b = idx / (D_CONV_ * D_INNER_);
    cs[idx] = bf2f(u[((size_t)b * L_SZ + (L_SZ - D_CONV_ + k)) * D_INNER_ + d]);
}

// x = silu(conv_b + depthwise_causal_conv(u))
// R8 rewrite: one thread owns 8 channels x 8 sequence rows. Weights (8x float4,
// 128B contiguous/aligned) + bias loaded ONCE and reused across 8 rows (the R7
// version re-gathered them per row: 64-line gathers dominated, 124us @ 810GB/s).
// u rows kept in a 4-deep sliding register window; zero-pad at t0==0 matches
// the reference's causal zero padding.
__global__ __launch_bounds__(256) void conv_silu_kernel(
    const unsigned short* __restrict__ u, const float* __restrict__ cw,
    const float* __restrict__ cb, unsigned short* __restrict__ x)
{
    const int g  = threadIdx.x;                 // channel group 0..255
    const int rb = blockIdx.x & (L_SZ / 8 - 1); // row block 0..511
    const int b  = blockIdx.x >> 9;
    const int d0 = g * 8;
    const int t0 = rb * 8;

    float4 wq[8];
#pragma unroll
    for (int e = 0; e < 8; e++) wq[e] = *(const float4*)(cw + (d0 + e) * 4);
    const float4 cb0 = *(const float4*)(cb + d0);
    const float4 cb1 = *(const float4*)(cb + d0 + 4);
    float bias[8];
    bias[0] = cb0.x; bias[1] = cb0.y; bias[2] = cb0.z; bias[3] = cb0.w;
    bias[4] = cb1.x; bias[5] = cb1.y; bias[6] = cb1.z; bias[7] = cb1.w;

    const size_t base = ((size_t)b * L_SZ + t0) * D_INNER_ + d0;
    const ushort8 zz = {0, 0, 0, 0, 0, 0, 0, 0};
    ushort8 r0, r1, r2, r3;
    r0 = (t0 >= 3) ? *(const ushort8*)(u + base - 3 * D_INNER_) : zz;
    r1 = (t0 >= 2) ? *(const ushort8*)(u + base - 2 * D_INNER_) : zz;
    r2 = (t0 >= 1) ? *(const ushort8*)(u + base - 1 * D_INNER_) : zz;
    r3 = *(const ushort8*)(u + base);

#pragma unroll
    for (int t = 0; t < 8; t++) {
        ushort8 o;
#pragma unroll
        for (int e = 0; e < 8; e++) {
            float acc = bias[e];
            acc += bf2f(r0[e]) * wq[e].x + bf2f(r1[e]) * wq[e].y
                 + bf2f(r2[e]) * wq[e].z + bf2f(r3[e]) * wq[e].w;
            o[e] = f2bf(silu_f(acc));
        }
        *(ushort8*)(x + base + (size_t)t * D_INNER_) = o;
        r0 = r1; r1 = r2; r2 = r3;
        if (t < 7) r3 = *(const ushort8*)(u + base + (size_t)(t + 1) * D_INNER_);
    }
}

// ---------------- chunk-parallel scan (proven R4) ----------------
__global__ __launch_bounds__(256) void scan_pass1(
    const unsigned short* __restrict__ delta, const unsigned short* __restrict__ x,
    const float* __restrict__ xdbl, const float* __restrict__ A_log,
    float* __restrict__ H, float* __restrict__ S)
{
    const int d = blockIdx.x * 256 + threadIdx.x;
    const int c = blockIdx.y;
    const int b = blockIdx.z;

    float a[D_STATE_];
#pragma unroll
    for (int n = 0; n < D_STATE_; n++) a[n] = -expf(A_log[d * D_STATE_ + n]);

    float s[D_STATE_];
#pragma unroll
    for (int n = 0; n < D_STATE_; n++) s[n] = 0.f;
    float sum = 0.f;

    const int t0 = c * CLEN;
    const float* xr = xdbl + ((size_t)b * L_SZ + t0) * 96;
    size_t base = ((size_t)b * L_SZ + t0) * D_INNER_ + d;

    for (int t = 0; t < CLEN; t++) {
        const float dlt = bf2f(delta[base]);
        const float xv  = bf2f(x[base]);
        float4 Bq[4];
#pragma unroll
        for (int q = 0; q < 4; q++) Bq[q] = *(const float4*)(xr + DT_RANK_ + q * 4);
        const float* Bf = (const float*)Bq;
        const float du = dlt * xv;
        sum += dlt;
#pragma unroll
        for (int n = 0; n < D_STATE_; n++)
            s[n] = __expf(dlt * a[n]) * s[n] + du * Bf[n];
        base += D_INNER_;
        xr += 96;
    }

    float* Hp = H + (((size_t)b * NCHUNK + c) * D_INNER_ + d) * D_STATE_;
#pragma unroll
    for (int q = 0; q < 4; q++)
        *(float4*)(Hp + q * 4) = make_float4(s[q*4], s[q*4+1], s[q*4+2], s[q*4+3]);
    S[((size_t)b * NCHUNK + c) * D_INNER_ + d] = sum;
}

__global__ __launch_bounds__(256) void scan_combine(
    const float* __restrict__ A_log, float* __restrict__ H,
    const float* __restrict__ S, float* __restrict__ last_state)
{
    const int idx = blockIdx.x * 256 + threadIdx.x;
    const int d = idx & (D_INNER_ - 1);
    const int b = idx >> 11;

    float a[D_STATE_];
#pragma unroll
    for (int n = 0; n < D_STATE_; n++) a[n] = -expf(A_log[d * D_STATE_ + n]);

    float cur[D_STATE_];
#pragma unroll
    for (int n = 0; n < D_STATE_; n++) cur[n] = 0.f;

    for (int c = 0; c < NCHUNK; c++) {
        float* Hp = H + (((size_t)b * NCHUNK + c) * D_INNER_ + d) * D_STATE_;
        const float Sv = S[((size_t)b * NCHUNK + c) * D_INNER_ + d];
        float h[D_STATE_];
#pragma unroll
        for (int q = 0; q < 4; q++) {
            const float4 v = *(const float4*)(Hp + q * 4);
            h[q*4] = v.x; h[q*4+1] = v.y; h[q*4+2] = v.z; h[q*4+3] = v.w;
        }
        float nxt[D_STATE_];
#pragma unroll
        for (int n = 0; n < D_STATE_; n++)
            nxt[n] = h[n] + __expf(a[n] * Sv) * cur[n];
#pragma unroll
        for (int q = 0; q < 4; q++)
            *(float4*)(Hp + q * 4) = make_float4(cur[q*4], cur[q*4+1], cur[q*4+2], cur[q*4+3]);
#pragma unroll
        for (int n = 0; n < D_STATE_; n++) cur[n] = nxt[n];
    }
#pragma unroll
    for (int n = 0; n < D_STATE_; n++)
        last_state[((size_t)b * D_INNER_ + d) * D_STATE_ + n] = cur[n];
}

__global__ __launch_bounds__(256) void scan_pass3(
    const unsigned short* __restrict__ delta, const unsigned short* __restrict__ x,
    const float* __restrict__ xdbl, const unsigned short* __restrict__ z,
    const float* __restrict__ A_log, const float* __restrict__ Dv,
    const float* __restrict__ H, unsigned short* __restrict__ y)
{
    const int d = blockIdx.x * 256 + threadIdx.x;
    const int c = blockIdx.y;
    const int b = blockIdx.z;

    float a[D_STATE_];
#pragma unroll
    for (int n = 0; n < D_STATE_; n++) a[n] = -expf(A_log[d * D_STATE_ + n]);
    const float Dd = Dv[d];

    const float* Hp = H + (((size_t)b * NCHUNK + c) * D_INNER_ + d) * D_STATE_;
    float s[D_STATE_];
#pragma unroll
    for (int q = 0; q < 4; q++) {
        const float4 v = *(const float4*)(Hp + q * 4);
        s[q*4] = v.x; s[q*4+1] = v.y; s[q*4+2] = v.z; s[q*4+3] = v.w;
    }

    const int t0 = c * CLEN;
    const float* xr = xdbl + ((size_t)b * L_SZ + t0) * 96;
    size_t base = ((size_t)b * L_SZ + t0) * D_INNER_ + d;

    for (int t = 0; t < CLEN; t++) {
        const float dlt = bf2f(delta[base]);
        const float xv  = bf2f(x[base]);
        const float zv  = bf2f(z[base]);
        float4 Bq[4], Cq[4];
#pragma unroll
        for (int q = 0; q < 4; q++) {
            Bq[q] = *(const float4*)(xr + DT_RANK_ + q * 4);
            Cq[q] = *(const float4*)(xr + DT_RANK_ + D_STATE_ + q * 4);
        }
        const float* Bf = (const float*)Bq;
        const float* Cf = (const float*)Cq;
        const float du = dlt * xv;
        float yv = 0.f;
#pragma unroll
        for (int n = 0; n < D_STATE_; n++) {
            s[n] = __expf(dlt * a[n]) * s[n] + du * Bf[n];
            yv += s[n] * Cf[n];
        }
        y[base] = f2bf((yv + xv * Dd) * silu_f(zv));
        base += D_INNER_;
        xr += 96;
    }
}

extern "C" void kernel_launch(void* const* d_in, const int* in_sizes, int n_in,
                              void* d_out, int out_size, void* d_ws, size_t ws_size,
                              hipStream_t stream) {
    const float* hidden     = (const float*)d_in[0];
    const float* in_proj_w  = (const float*)d_in[1];
    const float* conv_w     = (const float*)d_in[2];
    const float* conv_b     = (const float*)d_in[3];
    const float* x_proj_w   = (const float*)d_in[4];
    const float* dt_proj_w  = (const float*)d_in[5];
    const float* dt_proj_b  = (const float*)d_in[6];
    const float* A_log      = (const float*)d_in[7];
    const float* Dvec       = (const float*)d_in[8];
    const float* out_proj_w = (const float*)d_in[9];

    const size_t NT = (size_t)B_SZ * L_SZ * D_INNER_;   // 16,777,216 elems
    // ws layout (79,167,488 B total — identical to proven R4/R6/R7 footprint):
    //   r0   [0,     NT*2)   : u -> xproj partials P (25.2MB<32MB) -> delta -> y
    //   xb   [NT*2,  NT*4)   : hb+wib (pre-conv) -> x -> wob
    //   xdbl [NT*4,  +3.1MB) : x_dbl f32
    //   H / S                : chunk states / delta-sums
    const size_t off_xdbl = NT * 4;
    const size_t off_H    = off_xdbl + (size_t)B_SZ * L_SZ * 96 * 4;
    const size_t off_S    = off_H + (size_t)B_SZ * NCHUNK * D_INNER_ * D_STATE_ * 4;
    const size_t required = off_S + (size_t)B_SZ * NCHUNK * D_INNER_ * 4; // 79,167,488
    if (ws_size < required) return;

    char* wsb = (char*)d_ws;
    unsigned short* r0   = (unsigned short*)wsb;
    unsigned short* xb   = (unsigned short*)(wsb + NT * 2);
    float*          xdbl = (float*)(wsb + off_xdbl);
    float*          Hbuf = (float*)(wsb + off_H);
    float*          Sbuf = (float*)(wsb + off_S);
    float*          Pbuf = (float*)wsb;   // x_proj partials, in dead r0 window

    unsigned short* hb  = xb;                                   // 8192x1024
    unsigned short* wib = xb + (size_t)B_SZ * L_SZ * D_MODEL_;  // 4096x1024
    unsigned short* wob = xb;                                   // 1024x2048 after scan

    float* out = (float*)d_out;
    unsigned short* zb = (unsigned short*)d_out;  // z parked in out region
    float* conv_state_out = out + (size_t)B_SZ * L_SZ * D_MODEL_;
    float* last_state_out = conv_state_out + (size_t)B_SZ * D_INNER_ * D_CONV_;

    const int M = B_SZ * L_SZ;  // 8192
    dim3 blk(256);

    // 0) f32 -> bf16 conversions for MFMA operands
    f32_to_bf16_kernel<<<2048, blk, 0, stream>>>(hidden, hb, (int)(M * D_MODEL_ / 4));
    f32_to_bf16_kernel<<<1024, blk, 0, stream>>>(in_proj_w, wib, 2 * D_INNER_ * D_MODEL_ / 4);

    // 1) in_proj (MFMA): [u | z] = hidden @ in_proj_w^T
    gemm_mfma<1><<<dim3((2 * D_INNER_) / 128, M / 128), blk, 0, stream>>>(
        hb, wib, nullptr, r0, zb, M, 2 * D_INNER_, D_MODEL_);

    // 2) conv_state output
    conv_state_kernel<<<(B_SZ * D_INNER_ * D_CONV_ + 255) / 256, blk, 0, stream>>>(
        r0, conv_state_out);

    // 3) depthwise causal conv + SiLU: u -> x  (8 rows/thread, weights in regs)
    conv_silu_kernel<<<B_SZ * (L_SZ / 8), blk, 0, stream>>>(
        r0, conv_w, conv_b, xb);

    // 4) x_dbl = x @ x_proj_w^T (split-K MFMA into r0-resident partials, then reduce)
    gemm_xproj<<<dim3(M / 128, KS_XP), blk, 0, stream>>>(xb, x_proj_w, Pbuf);
    reduce_xproj<<<(M * 96 / 4) / 256, blk, 0, stream>>>(Pbuf, xdbl);

    // 5) delta = sp(sp(ts @ dt_w^T + b) + b) -> r0 (one-shot MFMA, overwrites P)
    gemm_dt<<<dim3(D_INNER_ / 128, M / 128), blk, 0, stream>>>(
        xdbl, dt_proj_w, dt_proj_b, r0);

    // 6) chunk-parallel selective scan (y in place over delta in r0)
    dim3 g13(D_INNER_ / 256, NCHUNK, B_SZ);
    scan_pass1<<<g13, blk, 0, stream>>>(r0, xb, xdbl, A_log, Hbuf, Sbuf);
    scan_combine<<<(B_SZ * D_INNER_) / 256, blk, 0, stream>>>(
        A_log, Hbuf, Sbuf, last_state_out);
    scan_pass3<<<g13, blk, 0, stream>>>(r0, xb, xdbl, zb, A_log, Dvec, Hbuf, r0);

    // 6b) convert out_proj_w (xb region now dead)
    f32_to_bf16_kernel<<<512, blk, 0, stream>>>(out_proj_w, wob, D_MODEL_ * D_INNER_ / 4);

    // 7) out = y @ out_proj_w^T (MFMA, f32 out)
    gemm_mfma<0><<<dim3(D_MODEL_ / 128, M / 128), blk, 0, stream>>>(
        r0, wob, out, nullptr, nullptr, M, D_MODEL_, D_INNER_);
}

// Round 10
// 475.835 us; speedup vs baseline: 9.7382x; 1.1809x over previous
//
#include <hip/hip_runtime.h>
#include <hip/hip_bf16.h>
#include <math.h>

#define B_SZ 2
#define L_SZ 4096
#define D_MODEL_ 1024
#define D_INNER_ 2048
#define D_STATE_ 16
#define D_CONV_ 4
#define DT_RANK_ 64
#define NCHUNK 32
#define CLEN 128   // NCHUNK * CLEN == L_SZ
#define KS_XP 8    // split-K factor for x_proj

typedef unsigned short ushort8 __attribute__((ext_vector_type(8)));
typedef unsigned short ushort4v __attribute__((ext_vector_type(4)));
typedef short mfrag8 __attribute__((ext_vector_type(8)));   // 8 bf16 (4 VGPR) MFMA A/B frag
typedef float facc4 __attribute__((ext_vector_type(4)));    // 4 f32 MFMA C/D frag

__device__ __forceinline__ float bf2f(unsigned short b) {
    return __uint_as_float(((unsigned)b) << 16);
}
__device__ __forceinline__ unsigned short f2bf(float f) {
    unsigned u = __float_as_uint(f);
    unsigned r = (u + 0x7fffu + ((u >> 16) & 1u)) >> 16;  // RNE
    return (unsigned short)r;
}
// R10: hw-transcendental softplus via HIP fast intrinsics __expf/__logf
// (v_exp_f32 + v_log_f32, ~5 VALU ops). R8's log1pf(__expf(x)) was a slow
// libm chain: gemm_dt 92% VALUBusy / 124us on 33.5M double-softplus evals.
// (R9's __exp2f spelling doesn't exist as a device intrinsic -> compile fail.)
__device__ __forceinline__ float softplus_f(float x) {
    const float r = __logf(1.f + __expf(x));
    return (x > 20.f) ? x : r;
}
__device__ __forceinline__ float silu_f(float x) {
    return x / (1.f + __expf(-x));
}
// async global -> LDS, 16B per lane (wave-uniform LDS base, per-lane global src)
__device__ __forceinline__ void gload_lds16(const void* g, void* l) {
    __builtin_amdgcn_global_load_lds(
        (const __attribute__((address_space(1))) unsigned int*)g,
        (__attribute__((address_space(3))) unsigned int*)l,
        16, 0, 0);
}
__device__ __forceinline__ ushort4v cvt4(float4 v) {
    ushort4v o;
    o[0] = f2bf(v.x); o[1] = f2bf(v.y); o[2] = f2bf(v.z); o[3] = f2bf(v.w);
    return o;
}

// ---------------------------------------------------------------------------
// f32 -> bf16 convert (vectorized)
__global__ __launch_bounds__(256) void f32_to_bf16_kernel(
    const float* __restrict__ in, unsigned short* __restrict__ out, int n4)
{
    for (size_t i = (size_t)blockIdx.x * 256 + threadIdx.x; i < (size_t)n4;
         i += (size_t)gridDim.x * 256) {
        *(ushort4v*)(out + i * 4) = cvt4(*(const float4*)(in + i * 4));
    }
}

// ---------------------------------------------------------------------------
// MFMA bf16 GEMM (PROVEN R6): C[M,N] = A[M,K] @ W[N,K]^T
// 128x128 tile, BK=32, 4 waves (2x2), each wave 64x64 via 4x4 16x16x32 frags.
// ACT 0: f32 out to Cf[M,N].  ACT 1: bf16 split at D_INNER_ -> U0 | U1.
template<int ACT>
__global__ __launch_bounds__(256) void gemm_mfma(
    const unsigned short* __restrict__ A,   // [M,K] bf16
    const unsigned short* __restrict__ W,   // [N,K] bf16
    float* __restrict__ Cf,
    unsigned short* __restrict__ U0, unsigned short* __restrict__ U1,
    int M, int N, int K)
{
    constexpr int BK = 32;
    __shared__ __align__(16) char lds[2 * 16384];  // [buf][A 8KB | W 8KB]

    const int tid = threadIdx.x;
    const int l   = tid & 63;
    const int wid = tid >> 6;
    const int wm  = wid >> 1;
    const int wn  = wid & 1;

    const int nwg  = gridDim.x * gridDim.y;
    const int flat = blockIdx.y * gridDim.x + blockIdx.x;
    const int swz  = (flat & 7) * (nwg >> 3) + (flat >> 3);
    const int m0   = (swz / gridDim.x) * 128;
    const int n0   = (swz % gridDim.x) * 128;

    const int rl   = l >> 2;
    const int slot = l & 3;
    const int xsl  = slot ^ ((rl >> 1) & 3);
    const char* a_src[2];
    const char* w_src[2];
#pragma unroll
    for (int i = 0; i < 2; i++) {
        const int r = wid * 32 + i * 16 + rl;
        a_src[i] = (const char*)A + ((size_t)(m0 + r) * K) * 2 + xsl * 16;
        w_src[i] = (const char*)W + ((size_t)(n0 + r) * K) * 2 + xsl * 16;
    }
    const int stg_off = wid * 32 * 64;

    const int srow = l & 15;
    const int kg   = l >> 4;
    const int lo   = srow * 64 + (kg ^ ((srow >> 1) & 3)) * 16;
    int a_off[4], b_off[4];
#pragma unroll
    for (int i = 0; i < 4; i++) {
        a_off[i] = (wm * 64 + i * 16) * 64 + lo;
        b_off[i] = (wn * 64 + i * 16) * 64 + lo;
    }

    const facc4 zf = {0.f, 0.f, 0.f, 0.f};
    facc4 acc[4][4];
#pragma unroll
    for (int i = 0; i < 4; i++)
#pragma unroll
        for (int j = 0; j < 4; j++) acc[i][j] = zf;

    const int KT = K / BK;
#pragma unroll
    for (int i = 0; i < 2; i++) {
        gload_lds16(a_src[i], lds + stg_off + i * 1024);
        gload_lds16(w_src[i], lds + 8192 + stg_off + i * 1024);
    }

    int cur = 0;
    for (int kt = 0; kt < KT; ++kt) {
        __syncthreads();
        if (kt + 1 < KT) {
            const int koff = (kt + 1) * BK * 2;
            char* dstA = lds + (cur ^ 1) * 16384 + stg_off;
#pragma unroll
            for (int i = 0; i < 2; i++) {
                gload_lds16(a_src[i] + koff, dstA + i * 1024);
                gload_lds16(w_src[i] + koff, dstA + 8192 + i * 1024);
            }
        }
        const char* base = lds + cur * 16384;
        mfrag8 af[4], bfr[4];
#pragma unroll
        for (int i = 0; i < 4; i++) af[i]  = *(const mfrag8*)(base + a_off[i]);
#pragma unroll
        for (int i = 0; i < 4; i++) bfr[i] = *(const mfrag8*)(base + 8192 + b_off[i]);
#pragma unroll
        for (int i = 0; i < 4; i++)
#pragma unroll
            for (int j = 0; j < 4; j++)
                acc[i][j] = __builtin_amdgcn_mfma_f32_16x16x32_bf16(af[i], bfr[j], acc[i][j], 0, 0, 0);
        cur ^= 1;
    }

    const int crow = (l >> 4) * 4;
    const int ccol = l & 15;
#pragma unroll
    for (int mi = 0; mi < 4; mi++) {
#pragma unroll
        for (int ni = 0; ni < 4; ni++) {
            const int col = n0 + wn * 64 + ni * 16 + ccol;
            const facc4 v = acc[mi][ni];
#pragma unroll
            for (int rr = 0; rr < 4; rr++) {
                const int row = m0 + wm * 64 + mi * 16 + crow + rr;
                if constexpr (ACT == 0) {
                    Cf[(size_t)row * N + col] = v[rr];
                } else {
                    if (col < D_INNER_)
                        U0[(size_t)row * D_INNER_ + col] = f2bf(v[rr]);
                    else
                        U1[(size_t)row * D_INNER_ + (col - D_INNER_)] = f2bf(v[rr]);
                }
            }
        }
    }
}

// ---------------------------------------------------------------------------
// x_proj split-K MFMA (proven R7)
__global__ __launch_bounds__(256) void gemm_xproj(
    const unsigned short* __restrict__ X,   // [8192][2048] bf16
    const float* __restrict__ Wf,           // [96][2048] f32
    float* __restrict__ P)                  // [KS_XP][8192][96] f32
{
    __shared__ __align__(16) char ldsA[128 * 128];  // 16 KB
    __shared__ __align__(16) char ldsW[96 * 128];   // 12 KB

    const int tid = threadIdx.x;
    const int l   = tid & 63;
    const int wid = tid >> 6;
    const int m0  = blockIdx.x * 128;
    const int kc  = blockIdx.y * (2048 / KS_XP);   // 256-wide K chunk

    const facc4 zf = {0.f, 0.f, 0.f, 0.f};
    facc4 acc[2][6];
#pragma unroll
    for (int i = 0; i < 2; i++)
#pragma unroll
        for (int j = 0; j < 6; j++) acc[i][j] = zf;

    for (int kt = 0; kt < 4; kt++) {
        const int k0 = kc + kt * 64;
        float4 wv[6];
#pragma unroll
        for (int j = 0; j < 6; j++) {
            const int i = tid + 256 * j;           // i < 1536
            const int row = i >> 4, q = i & 15;
            wv[j] = *(const float4*)(Wf + (size_t)row * 2048 + k0 + q * 4);
        }
        __syncthreads();
#pragma unroll
        for (int j2 = 0; j2 < 4; j2++) {
            const int row = wid * 32 + j2 * 8 + (l >> 3);
            const int xsl = (l & 7) ^ (row & 7);
            gload_lds16(X + (size_t)(m0 + row) * 2048 + k0 + xsl * 8,
                        ldsA + (wid * 32 + j2 * 8) * 128);
        }
#pragma unroll
        for (int j = 0; j < 6; j++) {
            const int i = tid + 256 * j;
            const int row = i >> 4, q = i & 15;
            *(ushort4v*)(ldsW + row * 128 + (((q >> 1) ^ (row & 7)) * 16) + (q & 1) * 8) = cvt4(wv[j]);
        }
        __syncthreads();
#pragma unroll
        for (int ks = 0; ks < 2; ks++) {
            mfrag8 af[2], bf6[6];
#pragma unroll
            for (int mi = 0; mi < 2; mi++) {
                const int row = wid * 32 + mi * 16 + (l & 15);
                af[mi] = *(const mfrag8*)(ldsA + row * 128 + (((ks * 4 + (l >> 4)) ^ (row & 7)) * 16));
            }
#pragma unroll
            for (int ni = 0; ni < 6; ni++) {
                const int row = ni * 16 + (l & 15);
                bf6[ni] = *(const mfrag8*)(ldsW + row * 128 + (((ks * 4 + (l >> 4)) ^ (row & 7)) * 16));
            }
#pragma unroll
            for (int mi = 0; mi < 2; mi++)
#pragma unroll
                for (int ni = 0; ni < 6; ni++)
                    acc[mi][ni] = __builtin_amdgcn_mfma_f32_16x16x32_bf16(af[mi], bf6[ni], acc[mi][ni], 0, 0, 0);
        }
    }

    const int crow = (l >> 4) * 4;
    const int ccol = l & 15;
    float* Pb = P + (size_t)blockIdx.y * (8192 * 96);
#pragma unroll
    for (int mi = 0; mi < 2; mi++) {
#pragma unroll
        for (int ni = 0; ni < 6; ni++) {
            const int col = ni * 16 + ccol;
            const facc4 v = acc[mi][ni];
#pragma unroll
            for (int rr = 0; rr < 4; rr++) {
                const int row = m0 + wid * 32 + mi * 16 + crow + rr;
                Pb[(size_t)row * 96 + col] = v[rr];
            }
        }
    }
}

// reduce split-K partials: xdbl = sum_ks P[ks]
__global__ __launch_bounds__(256) void reduce_xproj(
    const float* __restrict__ P, float* __restrict__ xdbl)
{
    const int i = blockIdx.x * 256 + threadIdx.x;   // float4 index < 196608
    const float4* p = (const float4*)P;
    float4 s = p[i];
#pragma unroll
    for (int k = 1; k < KS_XP; k++) {
        const float4 v = p[i + k * 196608];
        s.x += v.x; s.y += v.y; s.z += v.z; s.w += v.w;
    }
    ((float4*)xdbl)[i] = s;
}

// ---------------------------------------------------------------------------
// dt_proj one-shot MFMA (proven R7; R10: fast softplus epilogue)
__global__ __launch_bounds__(256) void gemm_dt(
    const float* __restrict__ xd,    // [8192][96] f32, cols 0..64 = ts
    const float* __restrict__ Wf,    // [2048][64] f32
    const float* __restrict__ bias,  // [2048]
    unsigned short* __restrict__ delta)  // [8192][2048] bf16
{
    __shared__ __align__(16) char ldsA[128 * 128];
    __shared__ __align__(16) char ldsW[128 * 128];

    const int tid = threadIdx.x;
    const int l   = tid & 63;
    const int wid = tid >> 6;
    const int wm  = wid >> 1;
    const int wn  = wid & 1;
    const int m0  = blockIdx.y * 128;
    const int n0  = blockIdx.x * 128;

#pragma unroll
    for (int j = 0; j < 8; j++) {
        const int i = tid + 256 * j;               // i < 2048
        const int row = i >> 4, q = i & 15;
        const float4 av = *(const float4*)(xd + (size_t)(m0 + row) * 96 + q * 4);
        const float4 wv = *(const float4*)(Wf + (size_t)(n0 + row) * 64 + q * 4);
        const int off = row * 128 + (((q >> 1) ^ (row & 7)) * 16) + (q & 1) * 8;
        *(ushort4v*)(ldsA + off) = cvt4(av);
        *(ushort4v*)(ldsW + off) = cvt4(wv);
    }
    __syncthreads();

    const facc4 zf = {0.f, 0.f, 0.f, 0.f};
    facc4 acc[4][4];
#pragma unroll
    for (int i = 0; i < 4; i++)
#pragma unroll
        for (int j = 0; j < 4; j++) acc[i][j] = zf;

#pragma unroll
    for (int ks = 0; ks < 2; ks++) {
        mfrag8 af[4], bfr[4];
#pragma unroll
        for (int mi = 0; mi < 4; mi++) {
            const int row = wm * 64 + mi * 16 + (l & 15);
            af[mi] = *(const mfrag8*)(ldsA + row * 128 + (((ks * 4 + (l >> 4)) ^ (row & 7)) * 16));
        }
#pragma unroll
        for (int ni = 0; ni < 4; ni++) {
            const int row = wn * 64 + ni * 16 + (l & 15);
            bfr[ni] = *(const mfrag8*)(ldsW + row * 128 + (((ks * 4 + (l >> 4)) ^ (row & 7)) * 16));
        }
#pragma unroll
        for (int mi = 0; mi < 4; mi++)
#pragma unroll
            for (int ni = 0; ni < 4; ni++)
                acc[mi][ni] = __builtin_amdgcn_mfma_f32_16x16x32_bf16(af[mi], bfr[ni], acc[mi][ni], 0, 0, 0);
    }

    const int crow = (l >> 4) * 4;
    const int ccol = l & 15;
#pragma unroll
    for (int mi = 0; mi < 4; mi++) {
#pragma unroll
        for (int ni = 0; ni < 4; ni++) {
            const int col = n0 + wn * 64 + ni * 16 + ccol;
            const float bb = bias[col];
            const facc4 v = acc[mi][ni];
#pragma unroll
            for (int rr = 0; rr < 4; rr++) {
                const int row = m0 + wm * 64 + mi * 16 + crow + rr;
                delta[(size_t)row * D_INNER_ + col] = f2bf(softplus_f(softplus_f(v[rr] + bb) + bb));
            }
        }
    }
}

// conv_state[b][d][k] = u[b, L-4+k, d]  (u bf16 -> f32 out)
__global__ __launch_bounds__(256) void conv_state_kernel(
    const unsigned short* __restrict__ u, float* __restrict__ cs)
{
    const int idx = blockIdx.x * 256 + threadIdx.x;
    if (idx >= B_SZ * D_INNER_ * D_CONV_) return;
    const int k = idx % D_CONV_;
    const int d = (idx / D_CONV_) % D_INNER_;
    const int b = idx / (D_CONV_ * D_INNER_);
    cs[idx] = bf2f(u[((size_t)b * L_SZ + (L_SZ - D_CONV_ + k)) * D_INNER_ + d]);
}

// x = silu(conv_b + depthwise_causal_conv(u))  (proven R8: 8 rows/thread)
__global__ __launch_bounds__(256) void conv_silu_kernel(
    const unsigned short* __restrict__ u, const float* __restrict__ cw,
    const float* __restrict__ cb, unsigned short* __restrict__ x)
{
    const int g  = threadIdx.x;                 // channel group 0..255
    const int rb = blockIdx.x & (L_SZ / 8 - 1); // row block 0..511
    const int b  = blockIdx.x >> 9;
    const int d0 = g * 8;
    const int t0 = rb * 8;

    float4 wq[8];
#pragma unroll
    for (int e = 0; e < 8; e++) wq[e] = *(const float4*)(cw + (d0 + e) * 4);
    const float4 cb0 = *(const float4*)(cb + d0);
    const float4 cb1 = *(const float4*)(cb + d0 + 4);
    float bias[8];
    bias[0] = cb0.x; bias[1] = cb0.y; bias[2] = cb0.z; bias[3] = cb0.w;
    bias[4] = cb1.x; bias[5] = cb1.y; bias[6] = cb1.z; bias[7] = cb1.w;

    const size_t base = ((size_t)b * L_SZ + t0) * D_INNER_ + d0;
    const ushort8 zz = {0, 0, 0, 0, 0, 0, 0, 0};
    ushort8 r0, r1, r2, r3;
    r0 = (t0 >= 3) ? *(const ushort8*)(u + base - 3 * D_INNER_) : zz;
    r1 = (t0 >= 2) ? *(const ushort8*)(u + base - 2 * D_INNER_) : zz;
    r2 = (t0 >= 1) ? *(const ushort8*)(u + base - 1 * D_INNER_) : zz;
    r3 = *(const ushort8*)(u + base);

#pragma unroll
    for (int t = 0; t < 8; t++) {
        ushort8 o;
#pragma unroll
        for (int e = 0; e < 8; e++) {
            float acc = bias[e];
            acc += bf2f(r0[e]) * wq[e].x + bf2f(r1[e]) * wq[e].y
                 + bf2f(r2[e]) * wq[e].z + bf2f(r3[e]) * wq[e].w;
            o[e] = f2bf(silu_f(acc));
        }
        *(ushort8*)(x + base + (size_t)t * D_INNER_) = o;
        r0 = r1; r1 = r2; r2 = r3;
        if (t < 7) r3 = *(const ushort8*)(u + base + (size_t)(t + 1) * D_INNER_);
    }
}

// ---------------- chunk-parallel scan (proven R4) ----------------
__global__ __launch_bounds__(256) void scan_pass1(
    const unsigned short* __restrict__ delta, const unsigned short* __restrict__ x,
    const float* __restrict__ xdbl, const float* __restrict__ A_log,
    float* __restrict__ H, float* __restrict__ S)
{
    const int d = blockIdx.x * 256 + threadIdx.x;
    const int c = blockIdx.y;
    const int b = blockIdx.z;

    float a[D_STATE_];
#pragma unroll
    for (int n = 0; n < D_STATE_; n++) a[n] = -expf(A_log[d * D_STATE_ + n]);

    float s[D_STATE_];
#pragma unroll
    for (int n = 0; n < D_STATE_; n++) s[n] = 0.f;
    float sum = 0.f;

    const int t0 = c * CLEN;
    const float* xr = xdbl + ((size_t)b * L_SZ + t0) * 96;
    size_t base = ((size_t)b * L_SZ + t0) * D_INNER_ + d;

    for (int t = 0; t < CLEN; t++) {
        const float dlt = bf2f(delta[base]);
        const float xv  = bf2f(x[base]);
        float4 Bq[4];
#pragma unroll
        for (int q = 0; q < 4; q++) Bq[q] = *(const float4*)(xr + DT_RANK_ + q * 4);
        const float* Bf = (const float*)Bq;
        const float du = dlt * xv;
        sum += dlt;
#pragma unroll
        for (int n = 0; n < D_STATE_; n++)
            s[n] = __expf(dlt * a[n]) * s[n] + du * Bf[n];
        base += D_INNER_;
        xr += 96;
    }

    float* Hp = H + (((size_t)b * NCHUNK + c) * D_INNER_ + d) * D_STATE_;
#pragma unroll
    for (int q = 0; q < 4; q++)
        *(float4*)(Hp + q * 4) = make_float4(s[q*4], s[q*4+1], s[q*4+2], s[q*4+3]);
    S[((size_t)b * NCHUNK + c) * D_INNER_ + d] = sum;
}

__global__ __launch_bounds__(256) void scan_combine(
    const float* __restrict__ A_log, float* __restrict__ H,
    const float* __restrict__ S, float* __restrict__ last_state)
{
    const int idx = blockIdx.x * 256 + threadIdx.x;
    const int d = idx & (D_INNER_ - 1);
    const int b = idx >> 11;

    float a[D_STATE_];
#pragma unroll
    for (int n = 0; n < D_STATE_; n++) a[n] = -expf(A_log[d * D_STATE_ + n]);

    float cur[D_STATE_];
#pragma unroll
    for (int n = 0; n < D_STATE_; n++) cur[n] = 0.f;

    for (int c = 0; c < NCHUNK; c++) {
        float* Hp = H + (((size_t)b * NCHUNK + c) * D_INNER_ + d) * D_STATE_;
        const float Sv = S[((size_t)b * NCHUNK + c) * D_INNER_ + d];
        float h[D_STATE_];
#pragma unroll
        for (int q = 0; q < 4; q++) {
            const float4 v = *(const float4*)(Hp + q * 4);
            h[q*4] = v.x; h[q*4+1] = v.y; h[q*4+2] = v.z; h[q*4+3] = v.w;
        }
        float nxt[D_STATE_];
#pragma unroll
        for (int n = 0; n < D_STATE_; n++)
            nxt[n] = h[n] + __expf(a[n] * Sv) * cur[n];
#pragma unroll
        for (int q = 0; q < 4; q++)
            *(float4*)(Hp + q * 4) = make_float4(cur[q*4], cur[q*4+1], cur[q*4+2], cur[q*4+3]);
#pragma unroll
        for (int n = 0; n < D_STATE_; n++) cur[n] = nxt[n];
    }
#pragma unroll
    for (int n = 0; n < D_STATE_; n++)
        last_state[((size_t)b * D_INNER_ + d) * D_STATE_ + n] = cur[n];
}

__global__ __launch_bounds__(256) void scan_pass3(
    const unsigned short* __restrict__ delta, const unsigned short* __restrict__ x,
    const float* __restrict__ xdbl, const unsigned short* __restrict__ z,
    const float* __restrict__ A_log, const float* __restrict__ Dv,
    const float* __restrict__ H, unsigned short* __restrict__ y)
{
    const int d = blockIdx.x * 256 + threadIdx.x;
    const int c = blockIdx.y;
    const int b = blockIdx.z;

    float a[D_STATE_];
#pragma unroll
    for (int n = 0; n < D_STATE_; n++) a[n] = -expf(A_log[d * D_STATE_ + n]);
    const float Dd = Dv[d];

    const float* Hp = H + (((size_t)b * NCHUNK + c) * D_INNER_ + d) * D_STATE_;
    float s[D_STATE_];
#pragma unroll
    for (int q = 0; q < 4; q++) {
        const float4 v = *(const float4*)(Hp + q * 4);
        s[q*4] = v.x; s[q*4+1] = v.y; s[q*4+2] = v.z; s[q*4+3] = v.w;
    }

    const int t0 = c * CLEN;
    const float* xr = xdbl + ((size_t)b * L_SZ + t0) * 96;
    size_t base = ((size_t)b * L_SZ + t0) * D_INNER_ + d;

    for (int t = 0; t < CLEN; t++) {
        const float dlt = bf2f(delta[base]);
        const float xv  = bf2f(x[base]);
        const float zv  = bf2f(z[base]);
        float4 Bq[4], Cq[4];
#pragma unroll
        for (int q = 0; q < 4; q++) {
            Bq[q] = *(const float4*)(xr + DT_RANK_ + q * 4);
            Cq[q] = *(const float4*)(xr + DT_RANK_ + D_STATE_ + q * 4);
        }
        const float* Bf = (const float*)Bq;
        const float* Cf = (const float*)Cq;
        const float du = dlt * xv;
        float yv = 0.f;
#pragma unroll
        for (int n = 0; n < D_STATE_; n++) {
            s[n] = __expf(dlt * a[n]) * s[n] + du * Bf[n];
            yv += s[n] * Cf[n];
        }
        y[base] = f2bf((yv + xv * Dd) * silu_f(zv));
        base += D_INNER_;
        xr += 96;
    }
}

extern "C" void kernel_launch(void* const* d_in, const int* in_sizes, int n_in,
                              void* d_out, int out_size, void* d_ws, size_t ws_size,
                              hipStream_t stream) {
    const float* hidden     = (const float*)d_in[0];
    const float* in_proj_w  = (const float*)d_in[1];
    const float* conv_w     = (const float*)d_in[2];
    const float* conv_b     = (const float*)d_in[3];
    const float* x_proj_w   = (const float*)d_in[4];
    const float* dt_proj_w  = (const float*)d_in[5];
    const float* dt_proj_b  = (const float*)d_in[6];
    const float* A_log      = (const float*)d_in[7];
    const float* Dvec       = (const float*)d_in[8];
    const float* out_proj_w = (const float*)d_in[9];

    const size_t NT = (size_t)B_SZ * L_SZ * D_INNER_;   // 16,777,216 elems
    // ws layout (79,167,488 B total — identical to proven R4/R6/R7/R8 footprint)
    const size_t off_xdbl = NT * 4;
    const size_t off_H    = off_xdbl + (size_t)B_SZ * L_SZ * 96 * 4;
    const size_t off_S    = off_H + (size_t)B_SZ * NCHUNK * D_INNER_ * D_STATE_ * 4;
    const size_t required = off_S + (size_t)B_SZ * NCHUNK * D_INNER_ * 4; // 79,167,488
    if (ws_size < required) return;

    char* wsb = (char*)d_ws;
    unsigned short* r0   = (unsigned short*)wsb;
    unsigned short* xb   = (unsigned short*)(wsb + NT * 2);
    float*          xdbl = (float*)(wsb + off_xdbl);
    float*          Hbuf = (float*)(wsb + off_H);
    float*          Sbuf = (float*)(wsb + off_S);
    float*          Pbuf = (float*)wsb;   // x_proj partials, in dead r0 window

    unsigned short* hb  = xb;                                   // 8192x1024
    unsigned short* wib = xb + (size_t)B_SZ * L_SZ * D_MODEL_;  // 4096x1024
    unsigned short* wob = xb;                                   // 1024x2048 after scan

    float* out = (float*)d_out;
    unsigned short* zb = (unsigned short*)d_out;  // z parked in out region
    float* conv_state_out = out + (size_t)B_SZ * L_SZ * D_MODEL_;
    float* last_state_out = conv_state_out + (size_t)B_SZ * D_INNER_ * D_CONV_;

    const int M = B_SZ * L_SZ;  // 8192
    dim3 blk(256);

    // 0) f32 -> bf16 conversions for MFMA operands
    f32_to_bf16_kernel<<<2048, blk, 0, stream>>>(hidden, hb, (int)(M * D_MODEL_ / 4));
    f32_to_bf16_kernel<<<1024, blk, 0, stream>>>(in_proj_w, wib, 2 * D_INNER_ * D_MODEL_ / 4);

    // 1) in_proj (MFMA): [u | z] = hidden @ in_proj_w^T
    gemm_mfma<1><<<dim3((2 * D_INNER_) / 128, M / 128), blk, 0, stream>>>(
        hb, wib, nullptr, r0, zb, M, 2 * D_INNER_, D_MODEL_);

    // 2) conv_state output
    conv_state_kernel<<<(B_SZ * D_INNER_ * D_CONV_ + 255) / 256, blk, 0, stream>>>(
        r0, conv_state_out);

    // 3) depthwise causal conv + SiLU: u -> x  (8 rows/thread, weights in regs)
    conv_silu_kernel<<<B_SZ * (L_SZ / 8), blk, 0, stream>>>(
        r0, conv_w, conv_b, xb);

    // 4) x_dbl = x @ x_proj_w^T (split-K MFMA into r0-resident partials, then reduce)
    gemm_xproj<<<dim3(M / 128, KS_XP), blk, 0, stream>>>(xb, x_proj_w, Pbuf);
    reduce_xproj<<<(M * 96 / 4) / 256, blk, 0, stream>>>(Pbuf, xdbl);

    // 5) delta = sp(sp(ts @ dt_w^T + b) + b) -> r0 (one-shot MFMA, overwrites P)
    gemm_dt<<<dim3(D_INNER_ / 128, M / 128), blk, 0, stream>>>(
        xdbl, dt_proj_w, dt_proj_b, r0);

    // 6) chunk-parallel selective scan (y in place over delta in r0)
    dim3 g13(D_INNER_ / 256, NCHUNK, B_SZ);
    scan_pass1<<<g13, blk, 0, stream>>>(r0, xb, xdbl, A_log, Hbuf, Sbuf);
    scan_combine<<<(B_SZ * D_INNER_) / 256, blk, 0, stream>>>(
        A_log, Hbuf, Sbuf, last_state_out);
    scan_pass3<<<g13, blk, 0, stream>>>(r0, xb, xdbl, zb, A_log, Dvec, Hbuf, r0);

    // 6b) convert out_proj_w (xb region now dead)
    f32_to_bf16_kernel<<<512, blk, 0, stream>>>(out_proj_w, wob, D_MODEL_ * D_INNER_ / 4);

    // 7) out = y @ out_proj_w^T (MFMA, f32 out)
    gemm_mfma<0><<<dim3(D_MODEL_ / 128, M / 128), blk, 0, stream>>>(
        r0, wob, out, nullptr, nullptr, M, D_MODEL_, D_INNER_);
}